// Round 9
// baseline (1006.970 us; speedup 1.0000x reference)
//
#include <hip/hip_runtime.h>

// Problem constants: B=128, L=512, D=256, H=128, 4H=512, both dirs fused NG=1024
#define NB 128
#define NL 512
#define ND 256
#define NG 1024

typedef __attribute__((ext_vector_type(8))) short bfv8;
typedef __attribute__((ext_vector_type(4))) float f32x4;

__device__ __forceinline__ unsigned short f2bf(float f) {
    unsigned u = __float_as_uint(f);
    u += 0x7fffu + ((u >> 16) & 1u);   // round-to-nearest-even
    return (unsigned short)(u >> 16);
}
__device__ __forceinline__ float bf2f(unsigned short u) {
    return __uint_as_float(((unsigned)u) << 16);
}

// ---------------------------------------------------------------------------
// 1) convert+transpose: xbt[l*128+b][d] = bf16(x[b][l][d])
// ---------------------------------------------------------------------------
__global__ __launch_bounds__(256) void convert_kernel(const float* __restrict__ x,
                                                      unsigned short* __restrict__ xbt) {
    size_t t = (size_t)blockIdx.x * 256 + threadIdx.x;
    size_t e = t * 4;                       // flat idx into x, 4 floats per thread
    int d = (int)(e & 255u);
    int l = (int)((e >> 8) & 511u);
    int b = (int)(e >> 17);
    float4 v = *(const float4*)(x + e);
    ushort4 o;
    o.x = f2bf(v.x); o.y = f2bf(v.y); o.z = f2bf(v.z); o.w = f2bf(v.w);
    *(ushort4*)(xbt + ((size_t)(l * NB + b)) * ND + d) = o;
}

// ---------------------------------------------------------------------------
// 2) fold: Weff[g][k] = sum_d Wih[g][d] * W_proj[d][k]  (bf16 out)
// ---------------------------------------------------------------------------
__global__ __launch_bounds__(256) void fold_kernel(const float* __restrict__ Wproj,
                                                   const float* __restrict__ bproj,
                                                   const float* __restrict__ Wih_f,
                                                   const float* __restrict__ b_f,
                                                   const float* __restrict__ Wih_b,
                                                   const float* __restrict__ b_b,
                                                   unsigned short* __restrict__ weff,
                                                   float* __restrict__ beff) {
    int g = blockIdx.x;            // 0..1023
    int k = threadIdx.x;           // 0..255
    const float* Wih = (g < 512) ? (Wih_f + (size_t)g * ND) : (Wih_b + (size_t)(g - 512) * ND);
    float acc = 0.f;
    for (int d = 0; d < ND; ++d)
        acc += Wih[d] * Wproj[(size_t)d * ND + k];
    weff[(size_t)g * ND + k] = f2bf(acc);
    if (k == 0) {
        float ab = (g < 512) ? b_f[g] : b_b[g - 512];
        for (int d = 0; d < ND; ++d) ab += Wih[d] * bproj[d];
        beff[g] = ab;
    }
}

// ---------------------------------------------------------------------------
// 3) pre-GEMM: C[r][g] = bf16( A[r][:] . Bw[g][:] + bias[g] )
//    128x128 tile, BK=32, 4 waves (2x2), 16x16x32 bf16 MFMA, XOR-swizzled LDS
// ---------------------------------------------------------------------------
__global__ __launch_bounds__(256, 2) void gemm_pre(const unsigned short* __restrict__ A,
                                                   const unsigned short* __restrict__ Bw,
                                                   const float* __restrict__ bias,
                                                   unsigned short* __restrict__ C) {
    __shared__ unsigned short As[128 * 32];
    __shared__ unsigned short Bs[128 * 32];
    const int tid = threadIdx.x;
    const int lane = tid & 63;
    const int wid = tid >> 6;
    const int m0 = blockIdx.y * 128;
    const int n0 = blockIdx.x * 128;
    const int wm = (wid >> 1) * 64;
    const int wn = (wid & 1) * 64;

    f32x4 acc[4][4] = {};

    const int row0 = tid >> 2;               // 0..63
    const int row1 = row0 + 64;
    const int co = (tid & 3) * 8;            // element col offset (8 bf16 = 16B)
    const int sw = (((tid & 3) << 4) ^ ((row0 & 3) << 4)) >> 1;

    bfv8 ra0 = *(const bfv8*)(A + (size_t)(m0 + row0) * ND + co);
    bfv8 ra1 = *(const bfv8*)(A + (size_t)(m0 + row1) * ND + co);
    bfv8 rb0 = *(const bfv8*)(Bw + (size_t)(n0 + row0) * ND + co);
    bfv8 rb1 = *(const bfv8*)(Bw + (size_t)(n0 + row1) * ND + co);

    for (int it = 0; it < 8; ++it) {
        __syncthreads();
        *(bfv8*)(As + row0 * 32 + sw) = ra0;
        *(bfv8*)(As + row1 * 32 + sw) = ra1;
        *(bfv8*)(Bs + row0 * 32 + sw) = rb0;
        *(bfv8*)(Bs + row1 * 32 + sw) = rb1;
        const int k1 = ((it + 1) & 7) * 32;
        ra0 = *(const bfv8*)(A + (size_t)(m0 + row0) * ND + k1 + co);
        ra1 = *(const bfv8*)(A + (size_t)(m0 + row1) * ND + k1 + co);
        rb0 = *(const bfv8*)(Bw + (size_t)(n0 + row0) * ND + k1 + co);
        rb1 = *(const bfv8*)(Bw + (size_t)(n0 + row1) * ND + k1 + co);
        __syncthreads();

        const int r = lane & 15;
        const int kq = lane >> 4;
        bfv8 af[4], bfr[4];
        #pragma unroll
        for (int m = 0; m < 4; ++m) {
            int rw = wm + m * 16 + r;
            af[m] = *(const bfv8*)(As + rw * 32 + (((kq << 4) ^ ((rw & 3) << 4)) >> 1));
        }
        #pragma unroll
        for (int n = 0; n < 4; ++n) {
            int rw = wn + n * 16 + r;
            bfr[n] = *(const bfv8*)(Bs + rw * 32 + (((kq << 4) ^ ((rw & 3) << 4)) >> 1));
        }
        #pragma unroll
        for (int m = 0; m < 4; ++m)
            #pragma unroll
            for (int n = 0; n < 4; ++n)
                acc[m][n] = __builtin_amdgcn_mfma_f32_16x16x32_bf16(af[m], bfr[n], acc[m][n], 0, 0, 0);
    }

    const int r = lane & 15;
    const int rq = lane >> 4;
    #pragma unroll
    for (int n = 0; n < 4; ++n) {
        int col = n0 + wn + n * 16 + r;
        float bv = bias[col];
        #pragma unroll
        for (int m = 0; m < 4; ++m) {
            #pragma unroll
            for (int v = 0; v < 4; ++v) {
                int rowg = m0 + wm + m * 16 + rq * 4 + v;
                C[(size_t)rowg * NG + col] = f2bf(acc[m][n][v] + bv);
            }
        }
    }
}

// ---------------------------------------------------------------------------
// 4) LSTM scan, MFMA formulation.
//    After r1-r8: every scalar/VALU structure ran at a constant ~2300-2450
//    cy/step with VGPR_Count pinned at <=88 (weights never resident) and ~2.5x
//    source VALU count — the compiler's weak path. Pivot to its strong path
//    (gemm_pre's pattern, proven resident registers):
//    block = 16 batches x 1 dir (grid 8x2 = 16 blocks, 512 thr = 8 waves).
//    Per step: gates[16x512] = h[16x128] @ Whh^T via 16x16x32 bf16 MFMA.
//    Wave w owns 4 gate-tiles at cols {g*128 + 16w}: i,f,g,o of hidden unit
//    16w+(lane&15) land in the SAME lane (C/D: col=lane&15, row=(lane>>4)*4+v)
//    -> c/h update lane-local, zero shuffles. Whh in persistent B-frags
//    (64 VGPR/lane, bf16-packed once). h in tiny padded LDS ([16][136],
//    double-buffered, conflict-free frag reads). pre staged into padded LDS
//    ([16][520]) by coalesced 32B/thread loads, double-buffered; loads for
//    step s+2 issued at step entry -> a full step of slack before the
//    barrier's vmcnt drain. ONE barrier/step. LDS padded to 82944B keeps the
//    1-block/CU occupancy pin (256-VGPR budget, r7-verified mechanism).
// ---------------------------------------------------------------------------
struct ScanSM {
    unsigned short h[2][16][136];   // [buf][batch][hid], +8 pad
    unsigned short p[2][16][520];   // [buf][batch][dir-half col], +8 pad
    char pin[40960];                // total 82944 B > 81920 -> 1 block/CU
};

#define MFMA16(a, b, c) __builtin_amdgcn_mfma_f32_16x16x32_bf16((a), (b), (c), 0, 0, 0)

#define ACT(V, C, CURB, NXTB)                                                  \
  {                                                                            \
    const int bb = q * 4 + (V);                                                \
    float pi = bf2f(sm.p[CURB][bb][hid]);                                      \
    float pf = bf2f(sm.p[CURB][bb][128 + hid]);                                \
    float pg = bf2f(sm.p[CURB][bb][256 + hid]);                                \
    float po = bf2f(sm.p[CURB][bb][384 + hid]);                                \
    float si = acci[V] + pi, sf = accf[V] + pf;                                \
    float sg = accg[V] + pg, so = acco[V] + po;                                \
    float ia = 1.f / (1.f + __expf(-si));                                      \
    float fa = 1.f / (1.f + __expf(-sf));                                      \
    float ga = 1.f - 2.f / (1.f + __expf(2.f * sg));                           \
    float oa = 1.f / (1.f + __expf(-so));                                      \
    C = fa * C + ia * ga;                                                      \
    float th = 1.f - 2.f / (1.f + __expf(2.f * C));                            \
    float hv = oa * th;                                                        \
    sm.h[NXTB][bb][hid] = f2bf(hv);                                            \
    out[((size_t)(16 * bg + bb) * NL + tt) * 256 + dir * 128 + hid] = hv;      \
  }

#define STEP(S, CURB, NXTB)                                                    \
  {                                                                            \
    int s2 = (S) + 2; if (s2 > 511) s2 = 511;                                  \
    int tts = dir ? (511 - s2) : s2;                                           \
    const unsigned short* gs = pbase + (size_t)tts * NB * NG;                  \
    bfv8 nx0 = *(const bfv8*)(gs);                                             \
    bfv8 nx1 = *(const bfv8*)(gs + 8);                                         \
    *(bfv8*)&sm.p[NXTB][srow][schk * 16]     = pr0;                            \
    *(bfv8*)&sm.p[NXTB][srow][schk * 16 + 8] = pr1;                            \
    bfv8 ha0 = *(const bfv8*)&sm.h[CURB][r][q * 8];                            \
    bfv8 ha1 = *(const bfv8*)&sm.h[CURB][r][32 + q * 8];                       \
    bfv8 ha2 = *(const bfv8*)&sm.h[CURB][r][64 + q * 8];                       \
    bfv8 ha3 = *(const bfv8*)&sm.h[CURB][r][96 + q * 8];                       \
    f32x4 z = {0.f, 0.f, 0.f, 0.f};                                            \
    f32x4 acci = MFMA16(ha0, bfr[0][0], z);                                    \
    f32x4 accf = MFMA16(ha0, bfr[1][0], z);                                    \
    f32x4 accg = MFMA16(ha0, bfr[2][0], z);                                    \
    f32x4 acco = MFMA16(ha0, bfr[3][0], z);                                    \
    acci = MFMA16(ha1, bfr[0][1], acci); accf = MFMA16(ha1, bfr[1][1], accf);  \
    accg = MFMA16(ha1, bfr[2][1], accg); acco = MFMA16(ha1, bfr[3][1], acco);  \
    acci = MFMA16(ha2, bfr[0][2], acci); accf = MFMA16(ha2, bfr[1][2], accf);  \
    accg = MFMA16(ha2, bfr[2][2], accg); acco = MFMA16(ha2, bfr[3][2], acco);  \
    acci = MFMA16(ha3, bfr[0][3], acci); accf = MFMA16(ha3, bfr[1][3], accf);  \
    accg = MFMA16(ha3, bfr[2][3], accg); acco = MFMA16(ha3, bfr[3][3], acco);  \
    int tt = dir ? (511 - (S)) : (S);                                          \
    ACT(0, c0, CURB, NXTB)                                                     \
    ACT(1, c1, CURB, NXTB)                                                     \
    ACT(2, c2, CURB, NXTB)                                                     \
    ACT(3, c3, CURB, NXTB)                                                     \
    pr0 = nx0; pr1 = nx1;                                                      \
    __syncthreads();                                                           \
  }

__global__ void __launch_bounds__(512, 2)
scan_kernel(const unsigned short* __restrict__ pre,
            const float* __restrict__ Whh_f,
            const float* __restrict__ Whh_b,
            float* __restrict__ out) {
    const int bg  = blockIdx.x;          // batch group: batches 16bg..16bg+15
    const int dir = blockIdx.y;
    const int tid = threadIdx.x;
    const int w   = tid >> 6;            // wave id: cols {g*128 + 16w + 0..15}
    const int lane = tid & 63;
    const int r   = lane & 15;           // frag row/col
    const int q   = lane >> 4;           // frag k-group / row-quad
    const int hid = 16 * w + r;

    __shared__ ScanSM sm;

    // ---- persistent B-fragments: Whh (f32 in memory) -> bf16, once ----
    const float* __restrict__ Wd = dir ? Whh_b : Whh_f;
    bfv8 bfr[4][4];                      // [gate][ktile]
    #pragma unroll
    for (int g = 0; g < 4; ++g) {
        #pragma unroll
        for (int kk = 0; kk < 4; ++kk) {
            const float* src = Wd + (size_t)(g * 128 + hid) * 128 + kk * 32 + q * 8;
            float4 lo = *(const float4*)(src);
            float4 hi = *(const float4*)(src + 4);
            bfv8 v;
            v[0] = (short)f2bf(lo.x); v[1] = (short)f2bf(lo.y);
            v[2] = (short)f2bf(lo.z); v[3] = (short)f2bf(lo.w);
            v[4] = (short)f2bf(hi.x); v[5] = (short)f2bf(hi.y);
            v[6] = (short)f2bf(hi.z); v[7] = (short)f2bf(hi.w);
            bfr[g][kk] = v;
        }
    }

    // ---- zero h[0] ----
    for (int i = tid; i < 16 * 136; i += 512)
        ((unsigned short*)sm.h[0])[i] = 0;

    float c0 = 0.f, c1 = 0.f, c2 = 0.f, c3 = 0.f;

    // ---- pre staging role: thread covers one 32B chunk of one batch row ----
    const int srow = tid >> 5;           // 0..15 (batch within group)
    const int schk = tid & 31;           // 32B chunk within 1KB dir-half row
    const unsigned short* pbase =
        pre + (size_t)(16 * bg + srow) * NG + dir * 512 + schk * 16;

    // prologue: stage s=0 into p[0]; load s=1 into pr
    {
        int tt0 = dir ? 511 : 0;
        const unsigned short* g0 = pbase + (size_t)tt0 * NB * NG;
        bfv8 s0a = *(const bfv8*)(g0);
        bfv8 s0b = *(const bfv8*)(g0 + 8);
        *(bfv8*)&sm.p[0][srow][schk * 16]     = s0a;
        *(bfv8*)&sm.p[0][srow][schk * 16 + 8] = s0b;
    }
    int tt1 = dir ? 510 : 1;
    const unsigned short* g1 = pbase + (size_t)tt1 * NB * NG;
    bfv8 pr0 = *(const bfv8*)(g1);
    bfv8 pr1 = *(const bfv8*)(g1 + 8);
    __syncthreads();

    for (int s = 0; s < 512; s += 2) {
        STEP(s, 0, 1)
        STEP(s + 1, 1, 0)
    }
}

// ---------------------------------------------------------------------------
// 5) LayerNorm in-place over last dim (256); one wave per row
// ---------------------------------------------------------------------------
__global__ __launch_bounds__(256) void ln_kernel(float* __restrict__ out,
                                                 const float* __restrict__ gamma,
                                                 const float* __restrict__ beta) {
    int row = blockIdx.x * 4 + (threadIdx.x >> 6);
    int lane = threadIdx.x & 63;
    float* p = out + (size_t)row * 256;
    float4 v = ((const float4*)p)[lane];
    float s = (v.x + v.y) + (v.z + v.w);
    float s2 = (v.x * v.x + v.y * v.y) + (v.z * v.z + v.w * v.w);
    #pragma unroll
    for (int o = 32; o > 0; o >>= 1) {
        s += __shfl_xor(s, o);
        s2 += __shfl_xor(s2, o);
    }
    float mu = s * (1.f / 256.f);
    float var = s2 * (1.f / 256.f) - mu * mu;
    float rs = rsqrtf(var + 1e-5f);
    float4 gv = ((const float4*)gamma)[lane];
    float4 bv = ((const float4*)beta)[lane];
    float4 r;
    r.x = (v.x - mu) * rs * gv.x + bv.x;
    r.y = (v.y - mu) * rs * gv.y + bv.y;
    r.z = (v.z - mu) * rs * gv.z + bv.z;
    r.w = (v.w - mu) * rs * gv.w + bv.w;
    ((float4*)p)[lane] = r;
}

// ---------------------------------------------------------------------------
extern "C" void kernel_launch(void* const* d_in, const int* in_sizes, int n_in,
                              void* d_out, int out_size, void* d_ws, size_t ws_size,
                              hipStream_t stream) {
    (void)in_sizes; (void)n_in; (void)out_size; (void)ws_size;
    const float* x     = (const float*)d_in[0];
    const float* Wproj = (const float*)d_in[1];
    const float* bproj = (const float*)d_in[2];
    const float* Wih_f = (const float*)d_in[3];
    const float* Whh_f = (const float*)d_in[4];
    const float* b_f   = (const float*)d_in[5];
    const float* Wih_b = (const float*)d_in[6];
    const float* Whh_b = (const float*)d_in[7];
    const float* b_b   = (const float*)d_in[8];
    const float* gamma = (const float*)d_in[9];
    const float* beta  = (const float*)d_in[10];
    float* out = (float*)d_out;

    // workspace layout
    char* ws = (char*)d_ws;
    unsigned short* pre  = (unsigned short*)ws;                   // 65536*1024*2 = 134217728
    unsigned short* xbt  = (unsigned short*)(ws + 134217728);     // 65536*256*2  =  33554432
    unsigned short* weff = (unsigned short*)(ws + 167772160);     // 1024*256*2   =    524288
    float*          beff = (float*)(ws + 168296448);              // 1024*4

    convert_kernel<<<16384, 256, 0, stream>>>(x, xbt);
    fold_kernel<<<1024, 256, 0, stream>>>(Wproj, bproj, Wih_f, b_f, Wih_b, b_b, weff, beff);
    gemm_pre<<<dim3(8, 512), 256, 0, stream>>>(xbt, weff, beff, pre);
    scan_kernel<<<dim3(8, 2), 512, 0, stream>>>(pre, Whh_f, Whh_b, out);
    ln_kernel<<<16384, 256, 0, stream>>>(out, gamma, beta);
}

// Round 10
// 983.237 us; speedup vs baseline: 1.0241x; 1.0241x over previous
//
#include <hip/hip_runtime.h>

// Problem constants: B=128, L=512, D=256, H=128, 4H=512, both dirs fused NG=1024
#define NB 128
#define NL 512
#define ND 256
#define NG 1024

typedef __attribute__((ext_vector_type(8))) short bfv8;
typedef __attribute__((ext_vector_type(4))) float f32x4;

__device__ __forceinline__ unsigned short f2bf(float f) {
    unsigned u = __float_as_uint(f);
    u += 0x7fffu + ((u >> 16) & 1u);   // round-to-nearest-even
    return (unsigned short)(u >> 16);
}
__device__ __forceinline__ float bf2f(unsigned short u) {
    return __uint_as_float(((unsigned)u) << 16);
}

// ---------------------------------------------------------------------------
// 1) convert+transpose: xbt[l*128+b][d] = bf16(x[b][l][d])
// ---------------------------------------------------------------------------
__global__ __launch_bounds__(256) void convert_kernel(const float* __restrict__ x,
                                                      unsigned short* __restrict__ xbt) {
    size_t t = (size_t)blockIdx.x * 256 + threadIdx.x;
    size_t e = t * 4;                       // flat idx into x, 4 floats per thread
    int d = (int)(e & 255u);
    int l = (int)((e >> 8) & 511u);
    int b = (int)(e >> 17);
    float4 v = *(const float4*)(x + e);
    ushort4 o;
    o.x = f2bf(v.x); o.y = f2bf(v.y); o.z = f2bf(v.z); o.w = f2bf(v.w);
    *(ushort4*)(xbt + ((size_t)(l * NB + b)) * ND + d) = o;
}

// ---------------------------------------------------------------------------
// 2) fold: Weff[g][k] = sum_d Wih[row(g)][d] * W_proj[d][k]  (bf16 out)
//    OUTPUT ROWS REORDERED for the scan: g = dir*512 + hid*4 + gate, so the
//    4 gate pre-activations of one (batch,hid) are contiguous (one uint2 read
//    in the scan's activation stage). Source Wih row = gate*128 + hid.
// ---------------------------------------------------------------------------
__global__ __launch_bounds__(256) void fold_kernel(const float* __restrict__ Wproj,
                                                   const float* __restrict__ bproj,
                                                   const float* __restrict__ Wih_f,
                                                   const float* __restrict__ b_f,
                                                   const float* __restrict__ Wih_b,
                                                   const float* __restrict__ b_b,
                                                   unsigned short* __restrict__ weff,
                                                   float* __restrict__ beff) {
    int g = blockIdx.x;            // 0..1023 (reordered output row)
    int k = threadIdx.x;           // 0..255
    int dirg = g >> 9;
    int rem  = g & 511;
    int hidg = rem >> 2;
    int gate = rem & 3;
    int srcrow = gate * 128 + hidg;
    const float* Wih = dirg ? (Wih_b + (size_t)srcrow * ND) : (Wih_f + (size_t)srcrow * ND);
    float acc = 0.f;
    for (int d = 0; d < ND; ++d)
        acc += Wih[d] * Wproj[(size_t)d * ND + k];
    weff[(size_t)g * ND + k] = f2bf(acc);
    if (k == 0) {
        float ab = dirg ? b_b[srcrow] : b_f[srcrow];
        for (int d = 0; d < ND; ++d) ab += Wih[d] * bproj[d];
        beff[g] = ab;
    }
}

// ---------------------------------------------------------------------------
// 3) pre-GEMM: C[r][g] = bf16( A[r][:] . Bw[g][:] + bias[g] )
//    128x128 tile, BK=32, 4 waves (2x2), 16x16x32 bf16 MFMA, XOR-swizzled LDS
// ---------------------------------------------------------------------------
__global__ __launch_bounds__(256, 2) void gemm_pre(const unsigned short* __restrict__ A,
                                                   const unsigned short* __restrict__ Bw,
                                                   const float* __restrict__ bias,
                                                   unsigned short* __restrict__ C) {
    __shared__ unsigned short As[128 * 32];
    __shared__ unsigned short Bs[128 * 32];
    const int tid = threadIdx.x;
    const int lane = tid & 63;
    const int wid = tid >> 6;
    const int m0 = blockIdx.y * 128;
    const int n0 = blockIdx.x * 128;
    const int wm = (wid >> 1) * 64;
    const int wn = (wid & 1) * 64;

    f32x4 acc[4][4] = {};

    const int row0 = tid >> 2;               // 0..63
    const int row1 = row0 + 64;
    const int co = (tid & 3) * 8;            // element col offset (8 bf16 = 16B)
    const int sw = (((tid & 3) << 4) ^ ((row0 & 3) << 4)) >> 1;

    bfv8 ra0 = *(const bfv8*)(A + (size_t)(m0 + row0) * ND + co);
    bfv8 ra1 = *(const bfv8*)(A + (size_t)(m0 + row1) * ND + co);
    bfv8 rb0 = *(const bfv8*)(Bw + (size_t)(n0 + row0) * ND + co);
    bfv8 rb1 = *(const bfv8*)(Bw + (size_t)(n0 + row1) * ND + co);

    for (int it = 0; it < 8; ++it) {
        __syncthreads();
        *(bfv8*)(As + row0 * 32 + sw) = ra0;
        *(bfv8*)(As + row1 * 32 + sw) = ra1;
        *(bfv8*)(Bs + row0 * 32 + sw) = rb0;
        *(bfv8*)(Bs + row1 * 32 + sw) = rb1;
        const int k1 = ((it + 1) & 7) * 32;
        ra0 = *(const bfv8*)(A + (size_t)(m0 + row0) * ND + k1 + co);
        ra1 = *(const bfv8*)(A + (size_t)(m0 + row1) * ND + k1 + co);
        rb0 = *(const bfv8*)(Bw + (size_t)(n0 + row0) * ND + k1 + co);
        rb1 = *(const bfv8*)(Bw + (size_t)(n0 + row1) * ND + k1 + co);
        __syncthreads();

        const int r = lane & 15;
        const int kq = lane >> 4;
        bfv8 af[4], bfr[4];
        #pragma unroll
        for (int m = 0; m < 4; ++m) {
            int rw = wm + m * 16 + r;
            af[m] = *(const bfv8*)(As + rw * 32 + (((kq << 4) ^ ((rw & 3) << 4)) >> 1));
        }
        #pragma unroll
        for (int n = 0; n < 4; ++n) {
            int rw = wn + n * 16 + r;
            bfr[n] = *(const bfv8*)(Bs + rw * 32 + (((kq << 4) ^ ((rw & 3) << 4)) >> 1));
        }
        #pragma unroll
        for (int m = 0; m < 4; ++m)
            #pragma unroll
            for (int n = 0; n < 4; ++n)
                acc[m][n] = __builtin_amdgcn_mfma_f32_16x16x32_bf16(af[m], bfr[n], acc[m][n], 0, 0, 0);
    }

    const int r = lane & 15;
    const int rq = lane >> 4;
    #pragma unroll
    for (int n = 0; n < 4; ++n) {
        int col = n0 + wn + n * 16 + r;
        float bv = bias[col];
        #pragma unroll
        for (int m = 0; m < 4; ++m) {
            #pragma unroll
            for (int v = 0; v < 4; ++v) {
                int rowg = m0 + wm + m * 16 + rq * 4 + v;
                C[(size_t)rowg * NG + col] = f2bf(acc[m][n][v] + bv);
            }
        }
    }
}

// ---------------------------------------------------------------------------
// 4) LSTM scan, MFMA formulation (r9 verified math) + RAW-BARRIER LOOP.
//    r9 post-mortem: __syncthreads() forces `s_waitcnt vmcnt(0)` before every
//    s_barrier -> per-step global load latency (~900cy) + store drain
//    serialized into each of 512 steps (4170 cy/step measured). Fix = T3/T4:
//    NO __syncthreads in the loop; per step:
//      sched_barrier(0); asm s_waitcnt lgkmcnt(0); s_barrier; sched_barrier(0)
//    Raw s_barrier has no vmcnt drain -> prefetched loads stay in flight with
//    compiler-COUNTED vmcnt; out-stores drain lazily. Prefetch deepened to 2
//    steps (prA/prB rotation, ~2 steps slack > HBM latency).
//    Structure: block = 16 batches x 1 dir (grid 8x2), 8 waves. Per step
//    gates[16x512] = h[16x128]@Whh^T via 16 MFMA/wave; wave w owns cols
//    {g*128+16w+r}: i,f,g,o of hid=16w+r land in the same lane -> lane-local
//    c/h update, zero shuffles. Whh persistent in 64 B-frag VGPRs (r9: VGPR=96,
//    resident, verified). pre staged via regs->LDS double buffer; p rows
//    reordered [hid*4+gate] -> activation reads are one uint2 per batch.
// ---------------------------------------------------------------------------
struct ScanSM {
    unsigned short h[2][16][136];   // [buf][batch][hid], +8 pad
    unsigned short p[2][16][512];   // [buf][batch][hid*4+gate]
    char pin[40960];                // total 82432 B > 81920 -> 1 block/CU
};

#define MFMA16(a, b, c) __builtin_amdgcn_mfma_f32_16x16x32_bf16((a), (b), (c), 0, 0, 0)

#define ACT(V, C, CURB, NXTB)                                                  \
  {                                                                            \
    const int bb = q * 4 + (V);                                                \
    uint2 pv = *(const uint2*)&sm.p[CURB][bb][4 * hid];                        \
    float pi = __uint_as_float(pv.x << 16);                                    \
    float pf = __uint_as_float(pv.x & 0xffff0000u);                            \
    float pg = __uint_as_float(pv.y << 16);                                    \
    float po = __uint_as_float(pv.y & 0xffff0000u);                            \
    float si = acci[V] + pi, sf = accf[V] + pf;                                \
    float sg = accg[V] + pg, so = acco[V] + po;                                \
    float ia = 1.f / (1.f + __expf(-si));                                      \
    float fa = 1.f / (1.f + __expf(-sf));                                      \
    float ga = 1.f - 2.f / (1.f + __expf(2.f * sg));                           \
    float oa = 1.f / (1.f + __expf(-so));                                      \
    C = fa * C + ia * ga;                                                      \
    float th = 1.f - 2.f / (1.f + __expf(2.f * C));                            \
    float hv = oa * th;                                                        \
    sm.h[NXTB][bb][hid] = f2bf(hv);                                            \
    out[((size_t)(16 * bg + bb) * NL + tt) * 256 + dir * 128 + hid] = hv;      \
  }

#define STEP(S, CURB, NXTB)                                                    \
  {                                                                            \
    int s3 = (S) + 3; if (s3 > 511) s3 = 511;                                  \
    int tts = dir ? (511 - s3) : s3;                                           \
    const unsigned short* gs = pbase + (size_t)tts * NB * NG;                  \
    bfv8 nx0 = *(const bfv8*)(gs);                                             \
    bfv8 nx1 = *(const bfv8*)(gs + 8);                                         \
    *(bfv8*)&sm.p[NXTB][srow][schk * 16]     = prA0;                           \
    *(bfv8*)&sm.p[NXTB][srow][schk * 16 + 8] = prA1;                           \
    bfv8 ha0 = *(const bfv8*)&sm.h[CURB][r][q * 8];                            \
    bfv8 ha1 = *(const bfv8*)&sm.h[CURB][r][32 + q * 8];                       \
    bfv8 ha2 = *(const bfv8*)&sm.h[CURB][r][64 + q * 8];                       \
    bfv8 ha3 = *(const bfv8*)&sm.h[CURB][r][96 + q * 8];                       \
    f32x4 z = {0.f, 0.f, 0.f, 0.f};                                            \
    f32x4 acci = MFMA16(ha0, bfr[0][0], z);                                    \
    f32x4 accf = MFMA16(ha0, bfr[1][0], z);                                    \
    f32x4 accg = MFMA16(ha0, bfr[2][0], z);                                    \
    f32x4 acco = MFMA16(ha0, bfr[3][0], z);                                    \
    acci = MFMA16(ha1, bfr[0][1], acci); accf = MFMA16(ha1, bfr[1][1], accf);  \
    accg = MFMA16(ha1, bfr[2][1], accg); acco = MFMA16(ha1, bfr[3][1], acco);  \
    acci = MFMA16(ha2, bfr[0][2], acci); accf = MFMA16(ha2, bfr[1][2], accf);  \
    accg = MFMA16(ha2, bfr[2][2], accg); acco = MFMA16(ha2, bfr[3][2], acco);  \
    acci = MFMA16(ha3, bfr[0][3], acci); accf = MFMA16(ha3, bfr[1][3], accf);  \
    accg = MFMA16(ha3, bfr[2][3], accg); acco = MFMA16(ha3, bfr[3][3], acco);  \
    int tt = dir ? (511 - (S)) : (S);                                          \
    ACT(0, c0, CURB, NXTB)                                                     \
    ACT(1, c1, CURB, NXTB)                                                     \
    ACT(2, c2, CURB, NXTB)                                                     \
    ACT(3, c3, CURB, NXTB)                                                     \
    prA0 = prB0; prA1 = prB1; prB0 = nx0; prB1 = nx1;                          \
    __builtin_amdgcn_sched_barrier(0);                                         \
    asm volatile("s_waitcnt lgkmcnt(0)");                                      \
    __builtin_amdgcn_s_barrier();                                              \
    __builtin_amdgcn_sched_barrier(0);                                         \
  }

__global__ void __launch_bounds__(512, 2)
scan_kernel(const unsigned short* __restrict__ pre,
            const float* __restrict__ Whh_f,
            const float* __restrict__ Whh_b,
            float* __restrict__ out) {
    const int bg  = blockIdx.x;          // batch group: batches 16bg..16bg+15
    const int dir = blockIdx.y;
    const int tid = threadIdx.x;
    const int w   = tid >> 6;            // wave id: cols {g*128 + 16w + 0..15}
    const int lane = tid & 63;
    const int r   = lane & 15;           // frag row/col
    const int q   = lane >> 4;           // frag k-group / row-quad
    const int hid = 16 * w + r;

    __shared__ ScanSM sm;

    // ---- persistent B-fragments: Whh (f32 in memory) -> bf16, once ----
    const float* __restrict__ Wd = dir ? Whh_b : Whh_f;
    bfv8 bfr[4][4];                      // [gate][ktile]
    #pragma unroll
    for (int g = 0; g < 4; ++g) {
        #pragma unroll
        for (int kk = 0; kk < 4; ++kk) {
            const float* src = Wd + (size_t)(g * 128 + hid) * 128 + kk * 32 + q * 8;
            float4 lo = *(const float4*)(src);
            float4 hi = *(const float4*)(src + 4);
            bfv8 v;
            v[0] = (short)f2bf(lo.x); v[1] = (short)f2bf(lo.y);
            v[2] = (short)f2bf(lo.z); v[3] = (short)f2bf(lo.w);
            v[4] = (short)f2bf(hi.x); v[5] = (short)f2bf(hi.y);
            v[6] = (short)f2bf(hi.z); v[7] = (short)f2bf(hi.w);
            bfr[g][kk] = v;
        }
    }

    // ---- zero h[0] ----
    for (int i = tid; i < 16 * 136; i += 512)
        ((unsigned short*)sm.h[0])[i] = 0;

    float c0 = 0.f, c1 = 0.f, c2 = 0.f, c3 = 0.f;

    // ---- pre staging role: thread covers one 32B chunk of one batch row ----
    const int srow = tid >> 5;           // 0..15 (batch within group)
    const int schk = tid & 31;           // 32B chunk within 1KB dir-half row
    const unsigned short* pbase =
        pre + (size_t)(16 * bg + srow) * NG + dir * 512 + schk * 16;

    // prologue: stage s=0 into p[0]; preload s=1 (prA) and s=2 (prB)
    {
        int tt0 = dir ? 511 : 0;
        const unsigned short* g0 = pbase + (size_t)tt0 * NB * NG;
        *(bfv8*)&sm.p[0][srow][schk * 16]     = *(const bfv8*)(g0);
        *(bfv8*)&sm.p[0][srow][schk * 16 + 8] = *(const bfv8*)(g0 + 8);
    }
    int tt1 = dir ? 510 : 1;
    const unsigned short* g1 = pbase + (size_t)tt1 * NB * NG;
    bfv8 prA0 = *(const bfv8*)(g1);
    bfv8 prA1 = *(const bfv8*)(g1 + 8);
    int tt2 = dir ? 509 : 2;
    const unsigned short* g2 = pbase + (size_t)tt2 * NB * NG;
    bfv8 prB0 = *(const bfv8*)(g2);
    bfv8 prB1 = *(const bfv8*)(g2 + 8);
    __syncthreads();

    for (int s = 0; s < 512; s += 2) {
        STEP(s, 0, 1)
        STEP(s + 1, 1, 0)
    }
}

// ---------------------------------------------------------------------------
// 5) LayerNorm in-place over last dim (256); one wave per row
// ---------------------------------------------------------------------------
__global__ __launch_bounds__(256) void ln_kernel(float* __restrict__ out,
                                                 const float* __restrict__ gamma,
                                                 const float* __restrict__ beta) {
    int row = blockIdx.x * 4 + (threadIdx.x >> 6);
    int lane = threadIdx.x & 63;
    float* p = out + (size_t)row * 256;
    float4 v = ((const float4*)p)[lane];
    float s = (v.x + v.y) + (v.z + v.w);
    float s2 = (v.x * v.x + v.y * v.y) + (v.z * v.z + v.w * v.w);
    #pragma unroll
    for (int o = 32; o > 0; o >>= 1) {
        s += __shfl_xor(s, o);
        s2 += __shfl_xor(s2, o);
    }
    float mu = s * (1.f / 256.f);
    float var = s2 * (1.f / 256.f) - mu * mu;
    float rs = rsqrtf(var + 1e-5f);
    float4 gv = ((const float4*)gamma)[lane];
    float4 bv = ((const float4*)beta)[lane];
    float4 r;
    r.x = (v.x - mu) * rs * gv.x + bv.x;
    r.y = (v.y - mu) * rs * gv.y + bv.y;
    r.z = (v.z - mu) * rs * gv.z + bv.z;
    r.w = (v.w - mu) * rs * gv.w + bv.w;
    ((float4*)p)[lane] = r;
}

// ---------------------------------------------------------------------------
extern "C" void kernel_launch(void* const* d_in, const int* in_sizes, int n_in,
                              void* d_out, int out_size, void* d_ws, size_t ws_size,
                              hipStream_t stream) {
    (void)in_sizes; (void)n_in; (void)out_size; (void)ws_size;
    const float* x     = (const float*)d_in[0];
    const float* Wproj = (const float*)d_in[1];
    const float* bproj = (const float*)d_in[2];
    const float* Wih_f = (const float*)d_in[3];
    const float* Whh_f = (const float*)d_in[4];
    const float* b_f   = (const float*)d_in[5];
    const float* Wih_b = (const float*)d_in[6];
    const float* Whh_b = (const float*)d_in[7];
    const float* b_b   = (const float*)d_in[8];
    const float* gamma = (const float*)d_in[9];
    const float* beta  = (const float*)d_in[10];
    float* out = (float*)d_out;

    // workspace layout
    char* ws = (char*)d_ws;
    unsigned short* pre  = (unsigned short*)ws;                   // 65536*1024*2 = 134217728
    unsigned short* xbt  = (unsigned short*)(ws + 134217728);     // 65536*256*2  =  33554432
    unsigned short* weff = (unsigned short*)(ws + 167772160);     // 1024*256*2   =    524288
    float*          beff = (float*)(ws + 168296448);              // 1024*4

    convert_kernel<<<16384, 256, 0, stream>>>(x, xbt);
    fold_kernel<<<1024, 256, 0, stream>>>(Wproj, bproj, Wih_f, b_f, Wih_b, b_b, weff, beff);
    gemm_pre<<<dim3(8, 512), 256, 0, stream>>>(xbt, weff, beff, pre);
    scan_kernel<<<dim3(8, 2), 512, 0, stream>>>(pre, Whh_f, Whh_b, out);
    ln_kernel<<<16384, 256, 0, stream>>>(out, gamma, beta);
}

// Round 11
// 741.544 us; speedup vs baseline: 1.3579x; 1.3259x over previous
//
#include <hip/hip_runtime.h>

// Problem constants: B=128, L=512, D=256, H=128, 4H=512, both dirs fused NG=1024
#define NB 128
#define NL 512
#define ND 256
#define NG 1024

typedef __attribute__((ext_vector_type(8))) short bfv8;
typedef __attribute__((ext_vector_type(4))) float f32x4;

__device__ __forceinline__ unsigned short f2bf(float f) {
    unsigned u = __float_as_uint(f);
    u += 0x7fffu + ((u >> 16) & 1u);   // round-to-nearest-even
    return (unsigned short)(u >> 16);
}
__device__ __forceinline__ float bf2f(unsigned short u) {
    return __uint_as_float(((unsigned)u) << 16);
}

// ---------------------------------------------------------------------------
// 1) convert+transpose: xbt[l*128+b][d] = bf16(x[b][l][d])
// ---------------------------------------------------------------------------
__global__ __launch_bounds__(256) void convert_kernel(const float* __restrict__ x,
                                                      unsigned short* __restrict__ xbt) {
    size_t t = (size_t)blockIdx.x * 256 + threadIdx.x;
    size_t e = t * 4;                       // flat idx into x, 4 floats per thread
    int d = (int)(e & 255u);
    int l = (int)((e >> 8) & 511u);
    int b = (int)(e >> 17);
    float4 v = *(const float4*)(x + e);
    ushort4 o;
    o.x = f2bf(v.x); o.y = f2bf(v.y); o.z = f2bf(v.z); o.w = f2bf(v.w);
    *(ushort4*)(xbt + ((size_t)(l * NB + b)) * ND + d) = o;
}

// ---------------------------------------------------------------------------
// 2) fold: Weff[g][k] = sum_d Wih[row(g)][d] * W_proj[d][k]  (bf16 out)
//    Output rows reordered: g = dir*512 + hid*4 + gate (scan reads the 4 gate
//    pre-activations of one (batch,hid) as one uint2). Source row gate*128+hid.
// ---------------------------------------------------------------------------
__global__ __launch_bounds__(256) void fold_kernel(const float* __restrict__ Wproj,
                                                   const float* __restrict__ bproj,
                                                   const float* __restrict__ Wih_f,
                                                   const float* __restrict__ b_f,
                                                   const float* __restrict__ Wih_b,
                                                   const float* __restrict__ b_b,
                                                   unsigned short* __restrict__ weff,
                                                   float* __restrict__ beff) {
    int g = blockIdx.x;            // 0..1023 (reordered output row)
    int k = threadIdx.x;           // 0..255
    int dirg = g >> 9;
    int rem  = g & 511;
    int hidg = rem >> 2;
    int gate = rem & 3;
    int srcrow = gate * 128 + hidg;
    const float* Wih = dirg ? (Wih_b + (size_t)srcrow * ND) : (Wih_f + (size_t)srcrow * ND);
    float acc = 0.f;
    for (int d = 0; d < ND; ++d)
        acc += Wih[d] * Wproj[(size_t)d * ND + k];
    weff[(size_t)g * ND + k] = f2bf(acc);
    if (k == 0) {
        float ab = dirg ? b_b[srcrow] : b_f[srcrow];
        for (int d = 0; d < ND; ++d) ab += Wih[d] * bproj[d];
        beff[g] = ab;
    }
}

// ---------------------------------------------------------------------------
// 3) pre-GEMM: C[r][g] = bf16( A[r][:] . Bw[g][:] + bias[g] )
//    128x128 tile, BK=32, 4 waves (2x2), 16x16x32 bf16 MFMA, XOR-swizzled LDS
// ---------------------------------------------------------------------------
__global__ __launch_bounds__(256, 2) void gemm_pre(const unsigned short* __restrict__ A,
                                                   const unsigned short* __restrict__ Bw,
                                                   const float* __restrict__ bias,
                                                   unsigned short* __restrict__ C) {
    __shared__ unsigned short As[128 * 32];
    __shared__ unsigned short Bs[128 * 32];
    const int tid = threadIdx.x;
    const int lane = tid & 63;
    const int wid = tid >> 6;
    const int m0 = blockIdx.y * 128;
    const int n0 = blockIdx.x * 128;
    const int wm = (wid >> 1) * 64;
    const int wn = (wid & 1) * 64;

    f32x4 acc[4][4] = {};

    const int row0 = tid >> 2;               // 0..63
    const int row1 = row0 + 64;
    const int co = (tid & 3) * 8;            // element col offset (8 bf16 = 16B)
    const int sw = (((tid & 3) << 4) ^ ((row0 & 3) << 4)) >> 1;

    bfv8 ra0 = *(const bfv8*)(A + (size_t)(m0 + row0) * ND + co);
    bfv8 ra1 = *(const bfv8*)(A + (size_t)(m0 + row1) * ND + co);
    bfv8 rb0 = *(const bfv8*)(Bw + (size_t)(n0 + row0) * ND + co);
    bfv8 rb1 = *(const bfv8*)(Bw + (size_t)(n0 + row1) * ND + co);

    for (int it = 0; it < 8; ++it) {
        __syncthreads();
        *(bfv8*)(As + row0 * 32 + sw) = ra0;
        *(bfv8*)(As + row1 * 32 + sw) = ra1;
        *(bfv8*)(Bs + row0 * 32 + sw) = rb0;
        *(bfv8*)(Bs + row1 * 32 + sw) = rb1;
        const int k1 = ((it + 1) & 7) * 32;
        ra0 = *(const bfv8*)(A + (size_t)(m0 + row0) * ND + k1 + co);
        ra1 = *(const bfv8*)(A + (size_t)(m0 + row1) * ND + k1 + co);
        rb0 = *(const bfv8*)(Bw + (size_t)(n0 + row0) * ND + k1 + co);
        rb1 = *(const bfv8*)(Bw + (size_t)(n0 + row1) * ND + k1 + co);
        __syncthreads();

        const int r = lane & 15;
        const int kq = lane >> 4;
        bfv8 af[4], bfr[4];
        #pragma unroll
        for (int m = 0; m < 4; ++m) {
            int rw = wm + m * 16 + r;
            af[m] = *(const bfv8*)(As + rw * 32 + (((kq << 4) ^ ((rw & 3) << 4)) >> 1));
        }
        #pragma unroll
        for (int n = 0; n < 4; ++n) {
            int rw = wn + n * 16 + r;
            bfr[n] = *(const bfv8*)(Bs + rw * 32 + (((kq << 4) ^ ((rw & 3) << 4)) >> 1));
        }
        #pragma unroll
        for (int m = 0; m < 4; ++m)
            #pragma unroll
            for (int n = 0; n < 4; ++n)
                acc[m][n] = __builtin_amdgcn_mfma_f32_16x16x32_bf16(af[m], bfr[n], acc[m][n], 0, 0, 0);
    }

    const int r = lane & 15;
    const int rq = lane >> 4;
    #pragma unroll
    for (int n = 0; n < 4; ++n) {
        int col = n0 + wn + n * 16 + r;
        float bv = bias[col];
        #pragma unroll
        for (int m = 0; m < 4; ++m) {
            #pragma unroll
            for (int v = 0; v < 4; ++v) {
                int rowg = m0 + wm + m * 16 + rq * 4 + v;
                C[(size_t)rowg * NG + col] = f2bf(acc[m][n][v] + bv);
            }
        }
    }
}

// ---------------------------------------------------------------------------
// 4) LSTM scan, MFMA + batch-replicated A + 1 ACT/lane.
//    r10 counters normalized by active CUs (16/256): per-CU VALU 80%, Mfma 12%
//    -> activation-transcendental-bound. Per-block MFMA work is FIXED at 128
//    MFMAs/step (M=16 min tile), but ACT scales with batches/block. New split:
//    4 batches/block, 64 blocks. A rows replicate each batch 4x (read
//    h[row>>2]) so C/D rows q*4+v all hold batch q -> EVERY lane does exactly
//    one ACT (batch=lane>>4, hid=16*wave+(lane&15); 512 tuples = 512 lanes).
//    Trans work/wave drops 4x and hides under the matrix pipe (separate
//    pipes). Raw-barrier loop (no vmcnt drain), 3-step prefetch, p rows
//    [hid*4+gate] -> uint2 ACT read; pads: h 140 (<=2-way), p 520 (<=2-way).
//    LDS pin >80KiB keeps 1 block/CU and the 256-VGPR allocator budget.
// ---------------------------------------------------------------------------
struct ScanSM {
    unsigned short h[2][4][140];    // [buf][batch][hid] bf16, pad->2-way max
    unsigned short p[2][4][520];    // [buf][batch][hid*4+gate] bf16
    char pin[71680];                // total 82240 B > 81920 -> 1 block/CU
};

#define MFMA16(a, b, c) __builtin_amdgcn_mfma_f32_16x16x32_bf16((a), (b), (c), 0, 0, 0)

#define STEP(S, CURB, NXTB)                                                    \
  {                                                                            \
    int s3 = (S) + 3; if (s3 > 511) s3 = 511;                                  \
    int tts = dir ? (511 - s3) : s3;                                           \
    bfv8 nx0;                                                                  \
    if (stg) {                                                                 \
        nx0 = *(const bfv8*)(pbase + (size_t)tts * NB * NG);                   \
        *(bfv8*)&sm.p[NXTB][srow][schk * 8] = prA0;                            \
    }                                                                          \
    bfv8 ha0 = *(const bfv8*)&sm.h[CURB][r >> 2][q * 8];                       \
    bfv8 ha1 = *(const bfv8*)&sm.h[CURB][r >> 2][32 + q * 8];                  \
    bfv8 ha2 = *(const bfv8*)&sm.h[CURB][r >> 2][64 + q * 8];                  \
    bfv8 ha3 = *(const bfv8*)&sm.h[CURB][r >> 2][96 + q * 8];                  \
    f32x4 z = {0.f, 0.f, 0.f, 0.f};                                            \
    f32x4 acci = MFMA16(ha0, bfr[0][0], z);                                    \
    f32x4 accf = MFMA16(ha0, bfr[1][0], z);                                    \
    f32x4 accg = MFMA16(ha0, bfr[2][0], z);                                    \
    f32x4 acco = MFMA16(ha0, bfr[3][0], z);                                    \
    acci = MFMA16(ha1, bfr[0][1], acci); accf = MFMA16(ha1, bfr[1][1], accf);  \
    accg = MFMA16(ha1, bfr[2][1], accg); acco = MFMA16(ha1, bfr[3][1], acco);  \
    acci = MFMA16(ha2, bfr[0][2], acci); accf = MFMA16(ha2, bfr[1][2], accf);  \
    accg = MFMA16(ha2, bfr[2][2], accg); acco = MFMA16(ha2, bfr[3][2], acco);  \
    acci = MFMA16(ha3, bfr[0][3], acci); accf = MFMA16(ha3, bfr[1][3], accf);  \
    accg = MFMA16(ha3, bfr[2][3], accg); acco = MFMA16(ha3, bfr[3][3], acco);  \
    int tt = dir ? (511 - (S)) : (S);                                          \
    {                                                                          \
        uint2 pv = *(const uint2*)&sm.p[CURB][q][4 * hid];                     \
        float pi = __uint_as_float(pv.x << 16);                                \
        float pf = __uint_as_float(pv.x & 0xffff0000u);                        \
        float pg = __uint_as_float(pv.y << 16);                                \
        float po = __uint_as_float(pv.y & 0xffff0000u);                        \
        float si = acci[0] + pi, sf = accf[0] + pf;                            \
        float sg = accg[0] + pg, so = acco[0] + po;                            \
        float ia = 1.f / (1.f + __expf(-si));                                  \
        float fa = 1.f / (1.f + __expf(-sf));                                  \
        float ga = 1.f - 2.f / (1.f + __expf(2.f * sg));                       \
        float oa = 1.f / (1.f + __expf(-so));                                  \
        c0 = fa * c0 + ia * ga;                                                \
        float th = 1.f - 2.f / (1.f + __expf(2.f * c0));                       \
        float hv = oa * th;                                                    \
        sm.h[NXTB][q][hid] = f2bf(hv);                                         \
        out[((size_t)(4 * bg + q) * NL + tt) * 256 + dir * 128 + hid] = hv;    \
    }                                                                          \
    if (stg) { prA0 = prB0; prB0 = nx0; }                                      \
    __builtin_amdgcn_sched_barrier(0);                                         \
    asm volatile("s_waitcnt lgkmcnt(0)");                                      \
    __builtin_amdgcn_s_barrier();                                              \
    __builtin_amdgcn_sched_barrier(0);                                         \
  }

__global__ void __launch_bounds__(512, 2)
scan_kernel(const unsigned short* __restrict__ pre,
            const float* __restrict__ Whh_f,
            const float* __restrict__ Whh_b,
            float* __restrict__ out) {
    const int bg  = blockIdx.x;          // batch group: batches 4bg..4bg+3
    const int dir = blockIdx.y;
    const int tid = threadIdx.x;
    const int w   = tid >> 6;            // wave id: hid cols 16w..16w+15
    const int lane = tid & 63;
    const int r   = lane & 15;           // frag row / hid sub-index
    const int q   = lane >> 4;           // frag k-group / BATCH (via replication)
    const int hid = 16 * w + r;

    __shared__ ScanSM sm;

    // ---- persistent B-fragments: Whh (f32 in memory) -> bf16, once ----
    const float* __restrict__ Wd = dir ? Whh_b : Whh_f;
    bfv8 bfr[4][4];                      // [gate][ktile]
    #pragma unroll
    for (int g = 0; g < 4; ++g) {
        #pragma unroll
        for (int kk = 0; kk < 4; ++kk) {
            const float* src = Wd + (size_t)(g * 128 + hid) * 128 + kk * 32 + q * 8;
            float4 lo = *(const float4*)(src);
            float4 hi = *(const float4*)(src + 4);
            bfv8 v;
            v[0] = (short)f2bf(lo.x); v[1] = (short)f2bf(lo.y);
            v[2] = (short)f2bf(lo.z); v[3] = (short)f2bf(lo.w);
            v[4] = (short)f2bf(hi.x); v[5] = (short)f2bf(hi.y);
            v[6] = (short)f2bf(hi.z); v[7] = (short)f2bf(hi.w);
            bfr[g][kk] = v;
        }
    }

    // ---- zero h (both buffers) ----
    for (int i = tid; i < 2 * 4 * 140; i += 512)
        ((unsigned short*)sm.h)[i] = 0;

    float c0 = 0.f;

    // ---- pre staging role: 256 threads cover 4 rows x 64 chunks of 16B ----
    const bool stg = (tid < 256);
    const int srow = (tid >> 6) & 3;     // 0..3 (batch within group)
    const int schk = tid & 63;           // 16B chunk within 1KB dir-half row
    const unsigned short* pbase =
        pre + (size_t)(4 * bg + srow) * NG + dir * 512 + schk * 8;

    bfv8 prA0, prB0;
    if (stg) {
        int tt0 = dir ? 511 : 0;
        *(bfv8*)&sm.p[0][srow][schk * 8] =
            *(const bfv8*)(pbase + (size_t)tt0 * NB * NG);
        int tt1 = dir ? 510 : 1;
        prA0 = *(const bfv8*)(pbase + (size_t)tt1 * NB * NG);
        int tt2 = dir ? 509 : 2;
        prB0 = *(const bfv8*)(pbase + (size_t)tt2 * NB * NG);
    }
    __syncthreads();

    for (int s = 0; s < 512; s += 2) {
        STEP(s, 0, 1)
        STEP(s + 1, 1, 0)
    }
}

// ---------------------------------------------------------------------------
// 5) LayerNorm in-place over last dim (256); one wave per row
// ---------------------------------------------------------------------------
__global__ __launch_bounds__(256) void ln_kernel(float* __restrict__ out,
                                                 const float* __restrict__ gamma,
                                                 const float* __restrict__ beta) {
    int row = blockIdx.x * 4 + (threadIdx.x >> 6);
    int lane = threadIdx.x & 63;
    float* p = out + (size_t)row * 256;
    float4 v = ((const float4*)p)[lane];
    float s = (v.x + v.y) + (v.z + v.w);
    float s2 = (v.x * v.x + v.y * v.y) + (v.z * v.z + v.w * v.w);
    #pragma unroll
    for (int o = 32; o > 0; o >>= 1) {
        s += __shfl_xor(s, o);
        s2 += __shfl_xor(s2, o);
    }
    float mu = s * (1.f / 256.f);
    float var = s2 * (1.f / 256.f) - mu * mu;
    float rs = rsqrtf(var + 1e-5f);
    float4 gv = ((const float4*)gamma)[lane];
    float4 bv = ((const float4*)beta)[lane];
    float4 r;
    r.x = (v.x - mu) * rs * gv.x + bv.x;
    r.y = (v.y - mu) * rs * gv.y + bv.y;
    r.z = (v.z - mu) * rs * gv.z + bv.z;
    r.w = (v.w - mu) * rs * gv.w + bv.w;
    ((float4*)p)[lane] = r;
}

// ---------------------------------------------------------------------------
extern "C" void kernel_launch(void* const* d_in, const int* in_sizes, int n_in,
                              void* d_out, int out_size, void* d_ws, size_t ws_size,
                              hipStream_t stream) {
    (void)in_sizes; (void)n_in; (void)out_size; (void)ws_size;
    const float* x     = (const float*)d_in[0];
    const float* Wproj = (const float*)d_in[1];
    const float* bproj = (const float*)d_in[2];
    const float* Wih_f = (const float*)d_in[3];
    const float* Whh_f = (const float*)d_in[4];
    const float* b_f   = (const float*)d_in[5];
    const float* Wih_b = (const float*)d_in[6];
    const float* Whh_b = (const float*)d_in[7];
    const float* b_b   = (const float*)d_in[8];
    const float* gamma = (const float*)d_in[9];
    const float* beta  = (const float*)d_in[10];
    float* out = (float*)d_out;

    // workspace layout
    char* ws = (char*)d_ws;
    unsigned short* pre  = (unsigned short*)ws;                   // 65536*1024*2 = 134217728
    unsigned short* xbt  = (unsigned short*)(ws + 134217728);     // 65536*256*2  =  33554432
    unsigned short* weff = (unsigned short*)(ws + 167772160);     // 1024*256*2   =    524288
    float*          beff = (float*)(ws + 168296448);              // 1024*4

    convert_kernel<<<16384, 256, 0, stream>>>(x, xbt);
    fold_kernel<<<1024, 256, 0, stream>>>(Wproj, bproj, Wih_f, b_f, Wih_b, b_b, weff, beff);
    gemm_pre<<<dim3(8, 512), 256, 0, stream>>>(xbt, weff, beff, pre);
    scan_kernel<<<dim3(32, 2), 512, 0, stream>>>(pre, Whh_f, Whh_b, out);
    ln_kernel<<<16384, 256, 0, stream>>>(out, gamma, beta);
}

// Round 12
// 686.916 us; speedup vs baseline: 1.4659x; 1.0795x over previous
//
#include <hip/hip_runtime.h>

// Problem constants: B=128, L=512, D=256, H=128, 4H=512, both dirs fused NG=1024
#define NB 128
#define NL 512
#define ND 256
#define NG 1024

typedef __attribute__((ext_vector_type(8))) short bfv8;
typedef __attribute__((ext_vector_type(4))) float f32x4;

__device__ __forceinline__ unsigned short f2bf(float f) {
    unsigned u = __float_as_uint(f);
    u += 0x7fffu + ((u >> 16) & 1u);   // round-to-nearest-even
    return (unsigned short)(u >> 16);
}
__device__ __forceinline__ float bf2f(unsigned short u) {
    return __uint_as_float(((unsigned)u) << 16);
}

// ---------------------------------------------------------------------------
// 1) convert+transpose: xbt[l*128+b][d] = bf16(x[b][l][d])
// ---------------------------------------------------------------------------
__global__ __launch_bounds__(256) void convert_kernel(const float* __restrict__ x,
                                                      unsigned short* __restrict__ xbt) {
    size_t t = (size_t)blockIdx.x * 256 + threadIdx.x;
    size_t e = t * 4;                       // flat idx into x, 4 floats per thread
    int d = (int)(e & 255u);
    int l = (int)((e >> 8) & 511u);
    int b = (int)(e >> 17);
    float4 v = *(const float4*)(x + e);
    ushort4 o;
    o.x = f2bf(v.x); o.y = f2bf(v.y); o.z = f2bf(v.z); o.w = f2bf(v.w);
    *(ushort4*)(xbt + ((size_t)(l * NB + b)) * ND + d) = o;
}

// ---------------------------------------------------------------------------
// 2) fold: Weff[g][k] = sum_d Wih[row(g)][d] * W_proj[d][k]  (bf16 out)
//    Output rows reordered: g = dir*512 + hid*4 + gate (scan reads the 4 gate
//    pre-activations of one (batch,hid) as one uint2). Source row gate*128+hid.
// ---------------------------------------------------------------------------
__global__ __launch_bounds__(256) void fold_kernel(const float* __restrict__ Wproj,
                                                   const float* __restrict__ bproj,
                                                   const float* __restrict__ Wih_f,
                                                   const float* __restrict__ b_f,
                                                   const float* __restrict__ Wih_b,
                                                   const float* __restrict__ b_b,
                                                   unsigned short* __restrict__ weff,
                                                   float* __restrict__ beff) {
    int g = blockIdx.x;            // 0..1023 (reordered output row)
    int k = threadIdx.x;           // 0..255
    int dirg = g >> 9;
    int rem  = g & 511;
    int hidg = rem >> 2;
    int gate = rem & 3;
    int srcrow = gate * 128 + hidg;
    const float* Wih = dirg ? (Wih_b + (size_t)srcrow * ND) : (Wih_f + (size_t)srcrow * ND);
    float acc = 0.f;
    for (int d = 0; d < ND; ++d)
        acc += Wih[d] * Wproj[(size_t)d * ND + k];
    weff[(size_t)g * ND + k] = f2bf(acc);
    if (k == 0) {
        float ab = dirg ? b_b[srcrow] : b_f[srcrow];
        for (int d = 0; d < ND; ++d) ab += Wih[d] * bproj[d];
        beff[g] = ab;
    }
}

// ---------------------------------------------------------------------------
// 3) pre-GEMM: C[r][g] = bf16( A[r][:] . Bw[g][:] + bias[g] )
//    128x128 tile, BK=32, 4 waves (2x2), 16x16x32 bf16 MFMA, XOR-swizzled LDS
// ---------------------------------------------------------------------------
__global__ __launch_bounds__(256, 2) void gemm_pre(const unsigned short* __restrict__ A,
                                                   const unsigned short* __restrict__ Bw,
                                                   const float* __restrict__ bias,
                                                   unsigned short* __restrict__ C) {
    __shared__ unsigned short As[128 * 32];
    __shared__ unsigned short Bs[128 * 32];
    const int tid = threadIdx.x;
    const int lane = tid & 63;
    const int wid = tid >> 6;
    const int m0 = blockIdx.y * 128;
    const int n0 = blockIdx.x * 128;
    const int wm = (wid >> 1) * 64;
    const int wn = (wid & 1) * 64;

    f32x4 acc[4][4] = {};

    const int row0 = tid >> 2;               // 0..63
    const int row1 = row0 + 64;
    const int co = (tid & 3) * 8;            // element col offset (8 bf16 = 16B)
    const int sw = (((tid & 3) << 4) ^ ((row0 & 3) << 4)) >> 1;

    bfv8 ra0 = *(const bfv8*)(A + (size_t)(m0 + row0) * ND + co);
    bfv8 ra1 = *(const bfv8*)(A + (size_t)(m0 + row1) * ND + co);
    bfv8 rb0 = *(const bfv8*)(Bw + (size_t)(n0 + row0) * ND + co);
    bfv8 rb1 = *(const bfv8*)(Bw + (size_t)(n0 + row1) * ND + co);

    for (int it = 0; it < 8; ++it) {
        __syncthreads();
        *(bfv8*)(As + row0 * 32 + sw) = ra0;
        *(bfv8*)(As + row1 * 32 + sw) = ra1;
        *(bfv8*)(Bs + row0 * 32 + sw) = rb0;
        *(bfv8*)(Bs + row1 * 32 + sw) = rb1;
        const int k1 = ((it + 1) & 7) * 32;
        ra0 = *(const bfv8*)(A + (size_t)(m0 + row0) * ND + k1 + co);
        ra1 = *(const bfv8*)(A + (size_t)(m0 + row1) * ND + k1 + co);
        rb0 = *(const bfv8*)(Bw + (size_t)(n0 + row0) * ND + k1 + co);
        rb1 = *(const bfv8*)(Bw + (size_t)(n0 + row1) * ND + k1 + co);
        __syncthreads();

        const int r = lane & 15;
        const int kq = lane >> 4;
        bfv8 af[4], bfr[4];
        #pragma unroll
        for (int m = 0; m < 4; ++m) {
            int rw = wm + m * 16 + r;
            af[m] = *(const bfv8*)(As + rw * 32 + (((kq << 4) ^ ((rw & 3) << 4)) >> 1));
        }
        #pragma unroll
        for (int n = 0; n < 4; ++n) {
            int rw = wn + n * 16 + r;
            bfr[n] = *(const bfv8*)(Bs + rw * 32 + (((kq << 4) ^ ((rw & 3) << 4)) >> 1));
        }
        #pragma unroll
        for (int m = 0; m < 4; ++m)
            #pragma unroll
            for (int n = 0; n < 4; ++n)
                acc[m][n] = __builtin_amdgcn_mfma_f32_16x16x32_bf16(af[m], bfr[n], acc[m][n], 0, 0, 0);
    }

    const int r = lane & 15;
    const int rq = lane >> 4;
    #pragma unroll
    for (int n = 0; n < 4; ++n) {
        int col = n0 + wn + n * 16 + r;
        float bv = bias[col];
        #pragma unroll
        for (int m = 0; m < 4; ++m) {
            #pragma unroll
            for (int v = 0; v < 4; ++v) {
                int rowg = m0 + wm + m * 16 + rq * 4 + v;
                C[(size_t)rowg * NG + col] = f2bf(acc[m][n][v] + bv);
            }
        }
    }
}

// ---------------------------------------------------------------------------
// 4) LSTM scan: dual-direction 1024-thread block, latency-overlap design.
//    r11 diagnosis: serial-chain-latency-bound (~3000cy/step; per-CU busy
//    ~50%). Levers: shorten the chain and overlap independent chains.
//    - Block = 1 batch, BOTH dirs: waves 0-7 fwd, 8-15 bwd. Two independent
//      recurrences at 4 waves/SIMD -> one dir's LDS/MFMA/ACT latency hides
//      under the other's. 1024-thr block also FORCES VGPR<=128 (block can't
//      launch otherwise) -> allocator must fit, no occupancy-chasing spiral.
//    - p direct-to-register: each lane loads its own uint2 (4 gate pre-acts,
//      reordered layout) 3 steps ahead (pP0/pP1/pP2 rotation). No p LDS.
//    - A-replication 16x: all A rows = h -> ds_read_b128 pure same-address
//      broadcast (conflict-free); every lane's acc[0] = its hid's gate.
//    - ONE raw barrier/step (no vmcnt drain): sched_barrier + lgkmcnt(0) +
//      s_barrier. LDS pin >80KiB -> 1 block/CU (static 16 waves/CU cap).
//    Grid: 128 blocks = 128 CUs, all 256 chains resident.
// ---------------------------------------------------------------------------
struct ScanSM {
    unsigned short h[2][2][136];   // [dir][buf][hid] bf16
    char pin[81000];               // total 82088 B > 81920 -> 1 block/CU
};

#define MFMA16(a, b, c) __builtin_amdgcn_mfma_f32_16x16x32_bf16((a), (b), (c), 0, 0, 0)

#define STEP(S, CURB, NXTB)                                                    \
  {                                                                            \
    int s3 = (S) + 3; if (s3 > 511) s3 = 511;                                  \
    int tts = dir ? (511 - s3) : s3;                                           \
    uint2 nx = *(const uint2*)(pb + (size_t)tts * NB * NG);                    \
    bfv8 ha0 = *(const bfv8*)&sm.h[dir][CURB][q * 8];                          \
    bfv8 ha1 = *(const bfv8*)&sm.h[dir][CURB][32 + q * 8];                     \
    bfv8 ha2 = *(const bfv8*)&sm.h[dir][CURB][64 + q * 8];                     \
    bfv8 ha3 = *(const bfv8*)&sm.h[dir][CURB][96 + q * 8];                     \
    f32x4 z = {0.f, 0.f, 0.f, 0.f};                                            \
    f32x4 acci = MFMA16(ha0, bfr[0][0], z);                                    \
    f32x4 accf = MFMA16(ha0, bfr[1][0], z);                                    \
    f32x4 accg = MFMA16(ha0, bfr[2][0], z);                                    \
    f32x4 acco = MFMA16(ha0, bfr[3][0], z);                                    \
    acci = MFMA16(ha1, bfr[0][1], acci); accf = MFMA16(ha1, bfr[1][1], accf);  \
    accg = MFMA16(ha1, bfr[2][1], accg); acco = MFMA16(ha1, bfr[3][1], acco);  \
    acci = MFMA16(ha2, bfr[0][2], acci); accf = MFMA16(ha2, bfr[1][2], accf);  \
    accg = MFMA16(ha2, bfr[2][2], accg); acco = MFMA16(ha2, bfr[3][2], acco);  \
    acci = MFMA16(ha3, bfr[0][3], acci); accf = MFMA16(ha3, bfr[1][3], accf);  \
    accg = MFMA16(ha3, bfr[2][3], accg); acco = MFMA16(ha3, bfr[3][3], acco);  \
    int tt = dir ? (511 - (S)) : (S);                                          \
    {                                                                          \
        float pi = __uint_as_float(pP0.x << 16);                               \
        float pf = __uint_as_float(pP0.x & 0xffff0000u);                       \
        float pg = __uint_as_float(pP0.y << 16);                               \
        float po = __uint_as_float(pP0.y & 0xffff0000u);                       \
        float si = acci[0] + pi, sf = accf[0] + pf;                            \
        float sg = accg[0] + pg, so = acco[0] + po;                            \
        float ia = 1.f / (1.f + __expf(-si));                                  \
        float fa = 1.f / (1.f + __expf(-sf));                                  \
        float ga = 1.f - 2.f / (1.f + __expf(2.f * sg));                       \
        float oa = 1.f / (1.f + __expf(-so));                                  \
        c0 = fa * c0 + ia * ga;                                                \
        float th = 1.f - 2.f / (1.f + __expf(2.f * c0));                       \
        float hv = oa * th;                                                    \
        if (q == 0) {                                                          \
            sm.h[dir][NXTB][hid] = f2bf(hv);                                   \
            out[((size_t)b * NL + tt) * 256 + dir * 128 + hid] = hv;           \
        }                                                                      \
    }                                                                          \
    pP0 = pP1; pP1 = pP2; pP2 = nx;                                            \
    __builtin_amdgcn_sched_barrier(0);                                         \
    asm volatile("s_waitcnt lgkmcnt(0)");                                      \
    __builtin_amdgcn_s_barrier();                                              \
    __builtin_amdgcn_sched_barrier(0);                                         \
  }

__global__ void __launch_bounds__(1024)
scan_kernel(const unsigned short* __restrict__ pre,
            const float* __restrict__ Whh_f,
            const float* __restrict__ Whh_b,
            float* __restrict__ out) {
    const int b    = blockIdx.x;         // batch 0..127
    const int tid  = threadIdx.x;
    const int dir  = tid >> 9;           // waves 0-7: fwd, 8-15: bwd
    const int w    = (tid >> 6) & 7;     // hid group: cols 16w..16w+15
    const int lane = tid & 63;
    const int r    = lane & 15;          // frag col -> hid sub-index
    const int q    = lane >> 4;          // frag k-group
    const int hid  = 16 * w + r;

    __shared__ ScanSM sm;

    // ---- persistent B-fragments: Whh (f32 in memory) -> bf16, once ----
    const float* __restrict__ Wd = dir ? Whh_b : Whh_f;
    bfv8 bfr[4][4];                      // [gate][ktile]
    #pragma unroll
    for (int g = 0; g < 4; ++g) {
        #pragma unroll
        for (int kk = 0; kk < 4; ++kk) {
            const float* src = Wd + (size_t)(g * 128 + hid) * 128 + kk * 32 + q * 8;
            float4 lo = *(const float4*)(src);
            float4 hi = *(const float4*)(src + 4);
            bfv8 v;
            v[0] = (short)f2bf(lo.x); v[1] = (short)f2bf(lo.y);
            v[2] = (short)f2bf(lo.z); v[3] = (short)f2bf(lo.w);
            v[4] = (short)f2bf(hi.x); v[5] = (short)f2bf(hi.y);
            v[6] = (short)f2bf(hi.z); v[7] = (short)f2bf(hi.w);
            bfr[g][kk] = v;
        }
    }

    // ---- zero h buf 0 for this dir (q==0 lanes cover all 128 hids/dir) ----
    if (q == 0) sm.h[dir][0][hid] = 0;

    float c0 = 0.f;

    // ---- per-lane pre pointer: uint2 at [tt][b][dir*512 + hid*4] ----
    const unsigned short* pb = pre + (size_t)b * NG + dir * 512 + hid * 4;

    int t0 = dir ? 511 : 0;
    int t1 = dir ? 510 : 1;
    int t2 = dir ? 509 : 2;
    uint2 pP0 = *(const uint2*)(pb + (size_t)t0 * NB * NG);
    uint2 pP1 = *(const uint2*)(pb + (size_t)t1 * NB * NG);
    uint2 pP2 = *(const uint2*)(pb + (size_t)t2 * NB * NG);
    __syncthreads();

    for (int s = 0; s < 512; s += 2) {
        STEP(s, 0, 1)
        STEP(s + 1, 1, 0)
    }
}

// ---------------------------------------------------------------------------
// 5) LayerNorm in-place over last dim (256); one wave per row
// ---------------------------------------------------------------------------
__global__ __launch_bounds__(256) void ln_kernel(float* __restrict__ out,
                                                 const float* __restrict__ gamma,
                                                 const float* __restrict__ beta) {
    int row = blockIdx.x * 4 + (threadIdx.x >> 6);
    int lane = threadIdx.x & 63;
    float* p = out + (size_t)row * 256;
    float4 v = ((const float4*)p)[lane];
    float s = (v.x + v.y) + (v.z + v.w);
    float s2 = (v.x * v.x + v.y * v.y) + (v.z * v.z + v.w * v.w);
    #pragma unroll
    for (int o = 32; o > 0; o >>= 1) {
        s += __shfl_xor(s, o);
        s2 += __shfl_xor(s2, o);
    }
    float mu = s * (1.f / 256.f);
    float var = s2 * (1.f / 256.f) - mu * mu;
    float rs = rsqrtf(var + 1e-5f);
    float4 gv = ((const float4*)gamma)[lane];
    float4 bv = ((const float4*)beta)[lane];
    float4 r;
    r.x = (v.x - mu) * rs * gv.x + bv.x;
    r.y = (v.y - mu) * rs * gv.y + bv.y;
    r.z = (v.z - mu) * rs * gv.z + bv.z;
    r.w = (v.w - mu) * rs * gv.w + bv.w;
    ((float4*)p)[lane] = r;
}

// ---------------------------------------------------------------------------
extern "C" void kernel_launch(void* const* d_in, const int* in_sizes, int n_in,
                              void* d_out, int out_size, void* d_ws, size_t ws_size,
                              hipStream_t stream) {
    (void)in_sizes; (void)n_in; (void)out_size; (void)ws_size;
    const float* x     = (const float*)d_in[0];
    const float* Wproj = (const float*)d_in[1];
    const float* bproj = (const float*)d_in[2];
    const float* Wih_f = (const float*)d_in[3];
    const float* Whh_f = (const float*)d_in[4];
    const float* b_f   = (const float*)d_in[5];
    const float* Wih_b = (const float*)d_in[6];
    const float* Whh_b = (const float*)d_in[7];
    const float* b_b   = (const float*)d_in[8];
    const float* gamma = (const float*)d_in[9];
    const float* beta  = (const float*)d_in[10];
    float* out = (float*)d_out;

    // workspace layout
    char* ws = (char*)d_ws;
    unsigned short* pre  = (unsigned short*)ws;                   // 65536*1024*2 = 134217728
    unsigned short* xbt  = (unsigned short*)(ws + 134217728);     // 65536*256*2  =  33554432
    unsigned short* weff = (unsigned short*)(ws + 167772160);     // 1024*256*2   =    524288
    float*          beff = (float*)(ws + 168296448);              // 1024*4

    convert_kernel<<<16384, 256, 0, stream>>>(x, xbt);
    fold_kernel<<<1024, 256, 0, stream>>>(Wproj, bproj, Wih_f, b_f, Wih_b, b_b, weff, beff);
    gemm_pre<<<dim3(8, 512), 256, 0, stream>>>(xbt, weff, beff, pre);
    scan_kernel<<<128, 1024, 0, stream>>>(pre, Whh_f, Whh_b, out);
    ln_kernel<<<16384, 256, 0, stream>>>(out, gamma, beta);
}

// Round 13
// 512.264 us; speedup vs baseline: 1.9657x; 1.3409x over previous
//
#include <hip/hip_runtime.h>

// Problem constants: B=128, L=512, D=256, H=128, 4H=512, both dirs fused NG=1024
#define NB 128
#define NL 512
#define ND 256
#define NG 1024

typedef __attribute__((ext_vector_type(8))) short bfv8;
typedef __attribute__((ext_vector_type(4))) float f32x4;

#define LOG2E 1.4426950408889634f
#define NSCALE (-1.4426950408889634f)   // i,f,o gate rows: t = -x*log2e
#define GSCALE (2.8853900817779268f)    // g gate rows: t = 2x*log2e

__device__ __forceinline__ unsigned short f2bf(float f) {
    unsigned u = __float_as_uint(f);
    u += 0x7fffu + ((u >> 16) & 1u);   // round-to-nearest-even
    return (unsigned short)(u >> 16);
}
__device__ __forceinline__ float bf2f(unsigned short u) {
    return __uint_as_float(((unsigned)u) << 16);
}

// ---------------------------------------------------------------------------
// 1) convert+transpose: xbt[l*128+b][d] = bf16(x[b][l][d])
// ---------------------------------------------------------------------------
__global__ __launch_bounds__(256) void convert_kernel(const float* __restrict__ x,
                                                      unsigned short* __restrict__ xbt) {
    size_t t = (size_t)blockIdx.x * 256 + threadIdx.x;
    size_t e = t * 4;                       // flat idx into x, 4 floats per thread
    int d = (int)(e & 255u);
    int l = (int)((e >> 8) & 511u);
    int b = (int)(e >> 17);
    float4 v = *(const float4*)(x + e);
    ushort4 o;
    o.x = f2bf(v.x); o.y = f2bf(v.y); o.z = f2bf(v.z); o.w = f2bf(v.w);
    *(ushort4*)(xbt + ((size_t)(l * NB + b)) * ND + d) = o;
}

// ---------------------------------------------------------------------------
// 2) fold: Weff[g][k] = scale(g) * sum_d Wih[row(g)][d] * W_proj[d][k]
//    Rows reordered g = dir*512 + hid*4 + gate; gate order i,f,g,o.
//    EXP2-DOMAIN scaling folded in: i,f,o rows x(-log2e), g rows x(+2 log2e)
//    -> scan's sigmoid = exp2+add+rcp, tanh = +1 fma. Bias scaled identically.
// ---------------------------------------------------------------------------
__global__ __launch_bounds__(256) void fold_kernel(const float* __restrict__ Wproj,
                                                   const float* __restrict__ bproj,
                                                   const float* __restrict__ Wih_f,
                                                   const float* __restrict__ b_f,
                                                   const float* __restrict__ Wih_b,
                                                   const float* __restrict__ b_b,
                                                   unsigned short* __restrict__ weff,
                                                   float* __restrict__ beff) {
    int g = blockIdx.x;            // 0..1023 (reordered output row)
    int k = threadIdx.x;           // 0..255
    int dirg = g >> 9;
    int rem  = g & 511;
    int hidg = rem >> 2;
    int gate = rem & 3;
    int srcrow = gate * 128 + hidg;
    float scale = (gate == 2) ? GSCALE : NSCALE;
    const float* Wih = dirg ? (Wih_b + (size_t)srcrow * ND) : (Wih_f + (size_t)srcrow * ND);
    float acc = 0.f;
    for (int d = 0; d < ND; ++d)
        acc += Wih[d] * Wproj[(size_t)d * ND + k];
    weff[(size_t)g * ND + k] = f2bf(acc * scale);
    if (k == 0) {
        float ab = dirg ? b_b[srcrow] : b_f[srcrow];
        for (int d = 0; d < ND; ++d) ab += Wih[d] * bproj[d];
        beff[g] = ab * scale;
    }
}

// ---------------------------------------------------------------------------
// 3) pre-GEMM: C[r][g] = bf16( A[r][:] . Bw[g][:] + bias[g] )
//    128x128 tile, BK=32, 4 waves (2x2), 16x16x32 bf16 MFMA, XOR-swizzled LDS
// ---------------------------------------------------------------------------
__global__ __launch_bounds__(256, 2) void gemm_pre(const unsigned short* __restrict__ A,
                                                   const unsigned short* __restrict__ Bw,
                                                   const float* __restrict__ bias,
                                                   unsigned short* __restrict__ C) {
    __shared__ unsigned short As[128 * 32];
    __shared__ unsigned short Bs[128 * 32];
    const int tid = threadIdx.x;
    const int lane = tid & 63;
    const int wid = tid >> 6;
    const int m0 = blockIdx.y * 128;
    const int n0 = blockIdx.x * 128;
    const int wm = (wid >> 1) * 64;
    const int wn = (wid & 1) * 64;

    f32x4 acc[4][4] = {};

    const int row0 = tid >> 2;               // 0..63
    const int row1 = row0 + 64;
    const int co = (tid & 3) * 8;            // element col offset (8 bf16 = 16B)
    const int sw = (((tid & 3) << 4) ^ ((row0 & 3) << 4)) >> 1;

    bfv8 ra0 = *(const bfv8*)(A + (size_t)(m0 + row0) * ND + co);
    bfv8 ra1 = *(const bfv8*)(A + (size_t)(m0 + row1) * ND + co);
    bfv8 rb0 = *(const bfv8*)(Bw + (size_t)(n0 + row0) * ND + co);
    bfv8 rb1 = *(const bfv8*)(Bw + (size_t)(n0 + row1) * ND + co);

    for (int it = 0; it < 8; ++it) {
        __syncthreads();
        *(bfv8*)(As + row0 * 32 + sw) = ra0;
        *(bfv8*)(As + row1 * 32 + sw) = ra1;
        *(bfv8*)(Bs + row0 * 32 + sw) = rb0;
        *(bfv8*)(Bs + row1 * 32 + sw) = rb1;
        const int k1 = ((it + 1) & 7) * 32;
        ra0 = *(const bfv8*)(A + (size_t)(m0 + row0) * ND + k1 + co);
        ra1 = *(const bfv8*)(A + (size_t)(m0 + row1) * ND + k1 + co);
        rb0 = *(const bfv8*)(Bw + (size_t)(n0 + row0) * ND + k1 + co);
        rb1 = *(const bfv8*)(Bw + (size_t)(n0 + row1) * ND + k1 + co);
        __syncthreads();

        const int r = lane & 15;
        const int kq = lane >> 4;
        bfv8 af[4], bfr[4];
        #pragma unroll
        for (int m = 0; m < 4; ++m) {
            int rw = wm + m * 16 + r;
            af[m] = *(const bfv8*)(As + rw * 32 + (((kq << 4) ^ ((rw & 3) << 4)) >> 1));
        }
        #pragma unroll
        for (int n = 0; n < 4; ++n) {
            int rw = wn + n * 16 + r;
            bfr[n] = *(const bfv8*)(Bs + rw * 32 + (((kq << 4) ^ ((rw & 3) << 4)) >> 1));
        }
        #pragma unroll
        for (int m = 0; m < 4; ++m)
            #pragma unroll
            for (int n = 0; n < 4; ++n)
                acc[m][n] = __builtin_amdgcn_mfma_f32_16x16x32_bf16(af[m], bfr[n], acc[m][n], 0, 0, 0);
    }

    const int r = lane & 15;
    const int rq = lane >> 4;
    #pragma unroll
    for (int n = 0; n < 4; ++n) {
        int col = n0 + wn + n * 16 + r;
        float bv = bias[col];
        #pragma unroll
        for (int m = 0; m < 4; ++m) {
            #pragma unroll
            for (int v = 0; v < 4; ++v) {
                int rowg = m0 + wm + m * 16 + rq * 4 + v;
                C[(size_t)rowg * NG + col] = f2bf(acc[m][n][v] + bv);
            }
        }
    }
}

// ---------------------------------------------------------------------------
// 4) LSTM scan: dual-direction 1024-thread block (r12 structure, verified) +
//    instruction diet. r12 was VALU-issue-bound (~72%/CU) at 2810cy/step.
//    Diet: (a) readfirstlane(dir) -> pre/out/LDS addressing is wave-uniform
//    SALU; pre load becomes saddr+v_off global_load_dwordx2, ZERO per-step
//    VALU addr math (uniform clamped row index, always in-bounds).
//    (b) exp2-domain gates (scaling folded into weff/Whh/bias): sigmoid =
//    v_exp+v_add+v_rcp via raw builtins (no Newton refinement), tanh = +fma.
//    (c) prefetch depth 2 -> renames cleanly in the 2-unrolled loop, no movs.
//    Keeps: waves 0-7 fwd / 8-15 bwd (independent chains, 4 waves/SIMD),
//    16x A-replication (broadcast ds_read, lane-local c/h, zero shuffles),
//    B-frags persistent (AGPR-resident per r12), ONE raw barrier/step
//    (counted vmcnt, no drain), LDS pin >80KiB -> 1 block/CU.
// ---------------------------------------------------------------------------
struct ScanSM {
    unsigned short h[2][2][136];   // [dir][buf][hid] bf16
    char pin[81000];               // total 82088 B > 81920 -> 1 block/CU
};

#define MFMA16(a, b, c) __builtin_amdgcn_mfma_f32_16x16x32_bf16((a), (b), (c), 0, 0, 0)

#define STEP(S, CURB, NXTB)                                                    \
  {                                                                            \
    int rr = (S) + 2; if (rr > 511) rr = 511;          /* uniform SALU */      \
    int tts = dirs ? (511 - rr) : rr;                                          \
    const unsigned short* rowp = pdb + (size_t)tts * (NB * NG);                \
    uint2 nx = *(const uint2*)(rowp + hid4);           /* saddr + v_off */     \
    bfv8 ha0 = *(const bfv8*)&sm.h[dirs][CURB][q * 8];                         \
    bfv8 ha1 = *(const bfv8*)&sm.h[dirs][CURB][32 + q * 8];                    \
    bfv8 ha2 = *(const bfv8*)&sm.h[dirs][CURB][64 + q * 8];                    \
    bfv8 ha3 = *(const bfv8*)&sm.h[dirs][CURB][96 + q * 8];                    \
    f32x4 z = {0.f, 0.f, 0.f, 0.f};                                            \
    f32x4 acci = MFMA16(ha0, bfr[0][0], z);                                    \
    f32x4 accf = MFMA16(ha0, bfr[1][0], z);                                    \
    f32x4 accg = MFMA16(ha0, bfr[2][0], z);                                    \
    f32x4 acco = MFMA16(ha0, bfr[3][0], z);                                    \
    acci = MFMA16(ha1, bfr[0][1], acci); accf = MFMA16(ha1, bfr[1][1], accf);  \
    accg = MFMA16(ha1, bfr[2][1], accg); acco = MFMA16(ha1, bfr[3][1], acco);  \
    acci = MFMA16(ha2, bfr[0][2], acci); accf = MFMA16(ha2, bfr[1][2], accf);  \
    accg = MFMA16(ha2, bfr[2][2], accg); acco = MFMA16(ha2, bfr[3][2], acco);  \
    acci = MFMA16(ha3, bfr[0][3], acci); accf = MFMA16(ha3, bfr[1][3], accf);  \
    accg = MFMA16(ha3, bfr[2][3], accg); acco = MFMA16(ha3, bfr[3][3], acco);  \
    int tt = dirs ? (511 - (S)) : (S);                                         \
    {                                                                          \
        float pi = __uint_as_float(pP0.x << 16);                               \
        float pf = __uint_as_float(pP0.x & 0xffff0000u);                       \
        float pg = __uint_as_float(pP0.y << 16);                               \
        float po = __uint_as_float(pP0.y & 0xffff0000u);                       \
        /* scaled domain: t_ifo = -x*log2e, t_g = 2x*log2e (folded) */         \
        float ia = __builtin_amdgcn_rcpf(1.f + __builtin_amdgcn_exp2f(acci[0] + pi)); \
        float fa = __builtin_amdgcn_rcpf(1.f + __builtin_amdgcn_exp2f(accf[0] + pf)); \
        float rg = __builtin_amdgcn_rcpf(1.f + __builtin_amdgcn_exp2f(accg[0] + pg)); \
        float oa = __builtin_amdgcn_rcpf(1.f + __builtin_amdgcn_exp2f(acco[0] + po)); \
        float ga = fmaf(-2.f, rg, 1.f);                                        \
        c0 = fmaf(fa, c0, ia * ga);                                            \
        float rc = __builtin_amdgcn_rcpf(1.f + __builtin_amdgcn_exp2f(c0 * GSCALE)); \
        float th = fmaf(-2.f, rc, 1.f);                                        \
        float hv = oa * th;                                                    \
        if (q == 0) {                                                          \
            sm.h[dirs][NXTB][hid] = f2bf(hv);                                  \
            orowb[(size_t)tt * 256 + hid] = hv;                                \
        }                                                                      \
    }                                                                          \
    pP0 = pP1; pP1 = nx;                                                       \
    __builtin_amdgcn_sched_barrier(0);                                         \
    asm volatile("s_waitcnt lgkmcnt(0)");                                      \
    __builtin_amdgcn_s_barrier();                                              \
    __builtin_amdgcn_sched_barrier(0);                                         \
  }

__global__ void __launch_bounds__(1024)
scan_kernel(const unsigned short* __restrict__ pre,
            const float* __restrict__ Whh_f,
            const float* __restrict__ Whh_b,
            float* __restrict__ out) {
    const int b    = blockIdx.x;         // batch 0..127
    const int tid  = threadIdx.x;
    const int dirs = __builtin_amdgcn_readfirstlane(tid >> 9);  // wave-uniform
    const int w    = (tid >> 6) & 7;     // hid group: cols 16w..16w+15
    const int lane = tid & 63;
    const int r    = lane & 15;          // frag col -> hid sub-index
    const int q    = lane >> 4;          // frag k-group
    const int hid  = 16 * w + r;
    const int hid4 = hid * 4;            // element offset of lane's uint2

    __shared__ ScanSM sm;

    // ---- persistent B-fragments: Whh (f32) -> bf16 with exp2-domain scale --
    const float* __restrict__ Wd = dirs ? Whh_b : Whh_f;
    bfv8 bfr[4][4];                      // [gate][ktile]
    #pragma unroll
    for (int g = 0; g < 4; ++g) {
        const float wscale = (g == 2) ? GSCALE : NSCALE;
        #pragma unroll
        for (int kk = 0; kk < 4; ++kk) {
            const float* src = Wd + (size_t)(g * 128 + hid) * 128 + kk * 32 + q * 8;
            float4 lo = *(const float4*)(src);
            float4 hi = *(const float4*)(src + 4);
            bfv8 v;
            v[0] = (short)f2bf(lo.x * wscale); v[1] = (short)f2bf(lo.y * wscale);
            v[2] = (short)f2bf(lo.z * wscale); v[3] = (short)f2bf(lo.w * wscale);
            v[4] = (short)f2bf(hi.x * wscale); v[5] = (short)f2bf(hi.y * wscale);
            v[6] = (short)f2bf(hi.z * wscale); v[7] = (short)f2bf(hi.w * wscale);
            bfr[g][kk] = v;
        }
    }

    // ---- zero h buf 0 for this dir ----
    if (q == 0) sm.h[dirs][0][hid] = 0;

    float c0 = 0.f;

    // ---- uniform bases: pre row base (dir half), out batch base ----
    const unsigned short* pdb = pre + (size_t)b * NG + dirs * 512;
    float* orowb = out + (size_t)b * NL * 256 + dirs * 128;

    int t0 = dirs ? 511 : 0;
    int t1 = dirs ? 510 : 1;
    uint2 pP0 = *(const uint2*)(pdb + (size_t)t0 * (NB * NG) + hid4);
    uint2 pP1 = *(const uint2*)(pdb + (size_t)t1 * (NB * NG) + hid4);
    __syncthreads();

    for (int s = 0; s < 512; s += 2) {
        STEP(s, 0, 1)
        STEP(s + 1, 1, 0)
    }
}

// ---------------------------------------------------------------------------
// 5) LayerNorm in-place over last dim (256); one wave per row
// ---------------------------------------------------------------------------
__global__ __launch_bounds__(256) void ln_kernel(float* __restrict__ out,
                                                 const float* __restrict__ gamma,
                                                 const float* __restrict__ beta) {
    int row = blockIdx.x * 4 + (threadIdx.x >> 6);
    int lane = threadIdx.x & 63;
    float* p = out + (size_t)row * 256;
    float4 v = ((const float4*)p)[lane];
    float s = (v.x + v.y) + (v.z + v.w);
    float s2 = (v.x * v.x + v.y * v.y) + (v.z * v.z + v.w * v.w);
    #pragma unroll
    for (int o = 32; o > 0; o >>= 1) {
        s += __shfl_xor(s, o);
        s2 += __shfl_xor(s2, o);
    }
    float mu = s * (1.f / 256.f);
    float var = s2 * (1.f / 256.f) - mu * mu;
    float rs = rsqrtf(var + 1e-5f);
    float4 gv = ((const float4*)gamma)[lane];
    float4 bv = ((const float4*)beta)[lane];
    float4 r;
    r.x = (v.x - mu) * rs * gv.x + bv.x;
    r.y = (v.y - mu) * rs * gv.y + bv.y;
    r.z = (v.z - mu) * rs * gv.z + bv.z;
    r.w = (v.w - mu) * rs * gv.w + bv.w;
    ((float4*)p)[lane] = r;
}

// ---------------------------------------------------------------------------
extern "C" void kernel_launch(void* const* d_in, const int* in_sizes, int n_in,
                              void* d_out, int out_size, void* d_ws, size_t ws_size,
                              hipStream_t stream) {
    (void)in_sizes; (void)n_in; (void)out_size; (void)ws_size;
    const float* x     = (const float*)d_in[0];
    const float* Wproj = (const float*)d_in[1];
    const float* bproj = (const float*)d_in[2];
    const float* Wih_f = (const float*)d_in[3];
    const float* Whh_f = (const float*)d_in[4];
    const float* b_f   = (const float*)d_in[5];
    const float* Wih_b = (const float*)d_in[6];
    const float* Whh_b = (const float*)d_in[7];
    const float* b_b   = (const float*)d_in[8];
    const float* gamma = (const float*)d_in[9];
    const float* beta  = (const float*)d_in[10];
    float* out = (float*)d_out;

    // workspace layout
    char* ws = (char*)d_ws;
    unsigned short* pre  = (unsigned short*)ws;                   // 65536*1024*2 = 134217728
    unsigned short* xbt  = (unsigned short*)(ws + 134217728);     // 65536*256*2  =  33554432
    unsigned short* weff = (unsigned short*)(ws + 167772160);     // 1024*256*2   =    524288
    float*          beff = (float*)(ws + 168296448);              // 1024*4

    convert_kernel<<<16384, 256, 0, stream>>>(x, xbt);
    fold_kernel<<<1024, 256, 0, stream>>>(Wproj, bproj, Wih_f, b_f, Wih_b, b_b, weff, beff);
    gemm_pre<<<dim3(8, 512), 256, 0, stream>>>(xbt, weff, beff, pre);
    scan_kernel<<<128, 1024, 0, stream>>>(pre, Whh_f, Whh_b, out);
    ln_kernel<<<16384, 256, 0, stream>>>(out, gamma, beta);
}

// Round 14
// 358.093 us; speedup vs baseline: 2.8120x; 1.4305x over previous
//
#include <hip/hip_runtime.h>

// Problem constants: B=128, L=512, D=256, H=128, 4H=512, both dirs fused NG=1024
#define NB 128
#define NL 512
#define ND 256
#define NG 1024

typedef __attribute__((ext_vector_type(8))) short bfv8;
typedef __attribute__((ext_vector_type(4))) float f32x4;

#define LOG2E 1.4426950408889634f
#define NSCALE (-1.4426950408889634f)   // i,f,o gate rows: t = -x*log2e
#define GSCALE (2.8853900817779268f)    // g gate rows: t = 2x*log2e

__device__ __forceinline__ unsigned short f2bf(float f) {
    unsigned u = __float_as_uint(f);
    u += 0x7fffu + ((u >> 16) & 1u);   // round-to-nearest-even
    return (unsigned short)(u >> 16);
}
__device__ __forceinline__ float bf2f(unsigned short u) {
    return __uint_as_float(((unsigned)u) << 16);
}

// ---------------------------------------------------------------------------
// 1) convert+transpose: xbt[l*128+b][d] = bf16(x[b][l][d])
// ---------------------------------------------------------------------------
__global__ __launch_bounds__(256) void convert_kernel(const float* __restrict__ x,
                                                      unsigned short* __restrict__ xbt) {
    size_t t = (size_t)blockIdx.x * 256 + threadIdx.x;
    size_t e = t * 4;                       // flat idx into x, 4 floats per thread
    int d = (int)(e & 255u);
    int l = (int)((e >> 8) & 511u);
    int b = (int)(e >> 17);
    float4 v = *(const float4*)(x + e);
    ushort4 o;
    o.x = f2bf(v.x); o.y = f2bf(v.y); o.z = f2bf(v.z); o.w = f2bf(v.w);
    *(ushort4*)(xbt + ((size_t)(l * NB + b)) * ND + d) = o;
}

// ---------------------------------------------------------------------------
// 2) fold: Weff[g][k] = scale(g) * sum_d Wih[row(g)][d] * W_proj[d][k]
//    Rows reordered g = dir*512 + hid*4 + gate; gate order i,f,g,o.
//    EXP2-DOMAIN scaling folded in: i,f,o rows x(-log2e), g rows x(+2 log2e)
// ---------------------------------------------------------------------------
__global__ __launch_bounds__(256) void fold_kernel(const float* __restrict__ Wproj,
                                                   const float* __restrict__ bproj,
                                                   const float* __restrict__ Wih_f,
                                                   const float* __restrict__ b_f,
                                                   const float* __restrict__ Wih_b,
                                                   const float* __restrict__ b_b,
                                                   unsigned short* __restrict__ weff,
                                                   float* __restrict__ beff) {
    int g = blockIdx.x;            // 0..1023 (reordered output row)
    int k = threadIdx.x;           // 0..255
    int dirg = g >> 9;
    int rem  = g & 511;
    int hidg = rem >> 2;
    int gate = rem & 3;
    int srcrow = gate * 128 + hidg;
    float scale = (gate == 2) ? GSCALE : NSCALE;
    const float* Wih = dirg ? (Wih_b + (size_t)srcrow * ND) : (Wih_f + (size_t)srcrow * ND);
    float acc = 0.f;
    for (int d = 0; d < ND; ++d)
        acc += Wih[d] * Wproj[(size_t)d * ND + k];
    weff[(size_t)g * ND + k] = f2bf(acc * scale);
    if (k == 0) {
        float ab = dirg ? b_b[srcrow] : b_f[srcrow];
        for (int d = 0; d < ND; ++d) ab += Wih[d] * bproj[d];
        beff[g] = ab * scale;
    }
}

// ---------------------------------------------------------------------------
// 3) pre-GEMM: C[r][g] = bf16( A[r][:] . Bw[g][:] + bias[g] )
//    128x128 tile, BK=32, 4 waves (2x2), 16x16x32 bf16 MFMA, XOR-swizzled LDS
// ---------------------------------------------------------------------------
__global__ __launch_bounds__(256, 2) void gemm_pre(const unsigned short* __restrict__ A,
                                                   const unsigned short* __restrict__ Bw,
                                                   const float* __restrict__ bias,
                                                   unsigned short* __restrict__ C) {
    __shared__ unsigned short As[128 * 32];
    __shared__ unsigned short Bs[128 * 32];
    const int tid = threadIdx.x;
    const int lane = tid & 63;
    const int wid = tid >> 6;
    const int m0 = blockIdx.y * 128;
    const int n0 = blockIdx.x * 128;
    const int wm = (wid >> 1) * 64;
    const int wn = (wid & 1) * 64;

    f32x4 acc[4][4] = {};

    const int row0 = tid >> 2;               // 0..63
    const int row1 = row0 + 64;
    const int co = (tid & 3) * 8;            // element col offset (8 bf16 = 16B)
    const int sw = (((tid & 3) << 4) ^ ((row0 & 3) << 4)) >> 1;

    bfv8 ra0 = *(const bfv8*)(A + (size_t)(m0 + row0) * ND + co);
    bfv8 ra1 = *(const bfv8*)(A + (size_t)(m0 + row1) * ND + co);
    bfv8 rb0 = *(const bfv8*)(Bw + (size_t)(n0 + row0) * ND + co);
    bfv8 rb1 = *(const bfv8*)(Bw + (size_t)(n0 + row1) * ND + co);

    for (int it = 0; it < 8; ++it) {
        __syncthreads();
        *(bfv8*)(As + row0 * 32 + sw) = ra0;
        *(bfv8*)(As + row1 * 32 + sw) = ra1;
        *(bfv8*)(Bs + row0 * 32 + sw) = rb0;
        *(bfv8*)(Bs + row1 * 32 + sw) = rb1;
        const int k1 = ((it + 1) & 7) * 32;
        ra0 = *(const bfv8*)(A + (size_t)(m0 + row0) * ND + k1 + co);
        ra1 = *(const bfv8*)(A + (size_t)(m0 + row1) * ND + k1 + co);
        rb0 = *(const bfv8*)(Bw + (size_t)(n0 + row0) * ND + k1 + co);
        rb1 = *(const bfv8*)(Bw + (size_t)(n0 + row1) * ND + k1 + co);
        __syncthreads();

        const int r = lane & 15;
        const int kq = lane >> 4;
        bfv8 af[4], bfr[4];
        #pragma unroll
        for (int m = 0; m < 4; ++m) {
            int rw = wm + m * 16 + r;
            af[m] = *(const bfv8*)(As + rw * 32 + (((kq << 4) ^ ((rw & 3) << 4)) >> 1));
        }
        #pragma unroll
        for (int n = 0; n < 4; ++n) {
            int rw = wn + n * 16 + r;
            bfr[n] = *(const bfv8*)(Bs + rw * 32 + (((kq << 4) ^ ((rw & 3) << 4)) >> 1));
        }
        #pragma unroll
        for (int m = 0; m < 4; ++m)
            #pragma unroll
            for (int n = 0; n < 4; ++n)
                acc[m][n] = __builtin_amdgcn_mfma_f32_16x16x32_bf16(af[m], bfr[n], acc[m][n], 0, 0, 0);
    }

    const int r = lane & 15;
    const int rq = lane >> 4;
    #pragma unroll
    for (int n = 0; n < 4; ++n) {
        int col = n0 + wn + n * 16 + r;
        float bv = bias[col];
        #pragma unroll
        for (int m = 0; m < 4; ++m) {
            #pragma unroll
            for (int v = 0; v < 4; ++v) {
                int rowg = m0 + wm + m * 16 + rq * 4 + v;
                C[(size_t)rowg * NG + col] = f2bf(acc[m][n][v] + bv);
            }
        }
    }
}

// ---------------------------------------------------------------------------
// 4) LSTM scan: ONE CHAIN PER BLOCK -> 256 blocks = ALL 256 CUs.
//    r13 fused both dirs into a 1024-thr block for 4 chain-waves/SIMD, but
//    that left 128 CUs idle. Splitting to one (batch,dir) chain per 512-thr
//    block keeps the identical per-wave step (16 cols, 16 MFMAs, 64 B-frag
//    regs, lean exp2/rcp ACT) while doubling active CUs. Single-chain step
//    wall at 2 waves/SIMD <= r13's 4-wave wall (less pipe contention, less
//    barrier jitter, same dependency chain) -> >=2x scan throughput bound.
//    dir is now blockIdx.y (kernel-scalar) -> pure SALU addressing.
//    Keeps: 16x A-replication (broadcast ds_read, lane-local c/h), B-frags
//    persistent (AGPR-resident), prefetch depth 2 via saddr+v_off loads,
//    ONE raw barrier/step (counted vmcnt, no drain), LDS pin >80KiB ->
//    statically 1 block/CU + 2-waves/SIMD allocator budget (r7 mechanism).
// ---------------------------------------------------------------------------
struct ScanSM {
    unsigned short h[2][136];      // [buf][hid] bf16
    char pin[81700];               // total 82244 B > 81920 -> 1 block/CU
};

#define MFMA16(a, b, c) __builtin_amdgcn_mfma_f32_16x16x32_bf16((a), (b), (c), 0, 0, 0)

#define STEP(S, CURB, NXTB)                                                    \
  {                                                                            \
    int rr = (S) + 2; if (rr > 511) rr = 511;          /* uniform SALU */      \
    int tts = dirs ? (511 - rr) : rr;                                          \
    const unsigned short* rowp = pdb + (size_t)tts * (NB * NG);                \
    uint2 nx = *(const uint2*)(rowp + hid4);           /* saddr + v_off */     \
    bfv8 ha0 = *(const bfv8*)&sm.h[CURB][q * 8];                               \
    bfv8 ha1 = *(const bfv8*)&sm.h[CURB][32 + q * 8];                          \
    bfv8 ha2 = *(const bfv8*)&sm.h[CURB][64 + q * 8];                          \
    bfv8 ha3 = *(const bfv8*)&sm.h[CURB][96 + q * 8];                          \
    f32x4 z = {0.f, 0.f, 0.f, 0.f};                                            \
    f32x4 acci = MFMA16(ha0, bfr[0][0], z);                                    \
    f32x4 accf = MFMA16(ha0, bfr[1][0], z);                                    \
    f32x4 accg = MFMA16(ha0, bfr[2][0], z);                                    \
    f32x4 acco = MFMA16(ha0, bfr[3][0], z);                                    \
    acci = MFMA16(ha1, bfr[0][1], acci); accf = MFMA16(ha1, bfr[1][1], accf);  \
    accg = MFMA16(ha1, bfr[2][1], accg); acco = MFMA16(ha1, bfr[3][1], acco);  \
    acci = MFMA16(ha2, bfr[0][2], acci); accf = MFMA16(ha2, bfr[1][2], accf);  \
    accg = MFMA16(ha2, bfr[2][2], accg); acco = MFMA16(ha2, bfr[3][2], acco);  \
    acci = MFMA16(ha3, bfr[0][3], acci); accf = MFMA16(ha3, bfr[1][3], accf);  \
    accg = MFMA16(ha3, bfr[2][3], accg); acco = MFMA16(ha3, bfr[3][3], acco);  \
    int tt = dirs ? (511 - (S)) : (S);                                         \
    {                                                                          \
        float pi = __uint_as_float(pP0.x << 16);                               \
        float pf = __uint_as_float(pP0.x & 0xffff0000u);                       \
        float pg = __uint_as_float(pP0.y << 16);                               \
        float po = __uint_as_float(pP0.y & 0xffff0000u);                       \
        /* scaled domain: t_ifo = -x*log2e, t_g = 2x*log2e (folded) */         \
        float ia = __builtin_amdgcn_rcpf(1.f + __builtin_amdgcn_exp2f(acci[0] + pi)); \
        float fa = __builtin_amdgcn_rcpf(1.f + __builtin_amdgcn_exp2f(accf[0] + pf)); \
        float rg = __builtin_amdgcn_rcpf(1.f + __builtin_amdgcn_exp2f(accg[0] + pg)); \
        float oa = __builtin_amdgcn_rcpf(1.f + __builtin_amdgcn_exp2f(acco[0] + po)); \
        float ga = fmaf(-2.f, rg, 1.f);                                        \
        c0 = fmaf(fa, c0, ia * ga);                                            \
        float rc = __builtin_amdgcn_rcpf(1.f + __builtin_amdgcn_exp2f(c0 * GSCALE)); \
        float th = fmaf(-2.f, rc, 1.f);                                        \
        float hv = oa * th;                                                    \
        if (q == 0) {                                                          \
            sm.h[NXTB][hid] = f2bf(hv);                                        \
            orowb[(size_t)tt * 256 + hid] = hv;                                \
        }                                                                      \
    }                                                                          \
    pP0 = pP1; pP1 = nx;                                                       \
    __builtin_amdgcn_sched_barrier(0);                                         \
    asm volatile("s_waitcnt lgkmcnt(0)");                                      \
    __builtin_amdgcn_s_barrier();                                              \
    __builtin_amdgcn_sched_barrier(0);                                         \
  }

__global__ void __launch_bounds__(512)
scan_kernel(const unsigned short* __restrict__ pre,
            const float* __restrict__ Whh_f,
            const float* __restrict__ Whh_b,
            float* __restrict__ out) {
    const int b    = blockIdx.x;         // batch 0..127
    const int dirs = blockIdx.y;         // 0 fwd, 1 bwd (kernel-scalar)
    const int tid  = threadIdx.x;
    const int w    = tid >> 6;           // hid group: cols 16w..16w+15
    const int lane = tid & 63;
    const int r    = lane & 15;          // frag col -> hid sub-index
    const int q    = lane >> 4;          // frag k-group
    const int hid  = 16 * w + r;
    const int hid4 = hid * 4;            // element offset of lane's uint2

    __shared__ ScanSM sm;

    // ---- persistent B-fragments: Whh (f32) -> bf16 with exp2-domain scale --
    const float* __restrict__ Wd = dirs ? Whh_b : Whh_f;
    bfv8 bfr[4][4];                      // [gate][ktile]
    #pragma unroll
    for (int g = 0; g < 4; ++g) {
        const float wscale = (g == 2) ? GSCALE : NSCALE;
        #pragma unroll
        for (int kk = 0; kk < 4; ++kk) {
            const float* src = Wd + (size_t)(g * 128 + hid) * 128 + kk * 32 + q * 8;
            float4 lo = *(const float4*)(src);
            float4 hi = *(const float4*)(src + 4);
            bfv8 v;
            v[0] = (short)f2bf(lo.x * wscale); v[1] = (short)f2bf(lo.y * wscale);
            v[2] = (short)f2bf(lo.z * wscale); v[3] = (short)f2bf(lo.w * wscale);
            v[4] = (short)f2bf(hi.x * wscale); v[5] = (short)f2bf(hi.y * wscale);
            v[6] = (short)f2bf(hi.z * wscale); v[7] = (short)f2bf(hi.w * wscale);
            bfr[g][kk] = v;
        }
    }

    // ---- zero h buf 0 ----
    if (q == 0) sm.h[0][hid] = 0;

    float c0 = 0.f;

    // ---- uniform bases: pre row base (dir half), out batch base ----
    const unsigned short* pdb = pre + (size_t)b * NG + dirs * 512;
    float* orowb = out + (size_t)b * NL * 256 + dirs * 128;

    int t0 = dirs ? 511 : 0;
    int t1 = dirs ? 510 : 1;
    uint2 pP0 = *(const uint2*)(pdb + (size_t)t0 * (NB * NG) + hid4);
    uint2 pP1 = *(const uint2*)(pdb + (size_t)t1 * (NB * NG) + hid4);
    __syncthreads();

    for (int s = 0; s < 512; s += 2) {
        STEP(s, 0, 1)
        STEP(s + 1, 1, 0)
    }
}

// ---------------------------------------------------------------------------
// 5) LayerNorm in-place over last dim (256); one wave per row
// ---------------------------------------------------------------------------
__global__ __launch_bounds__(256) void ln_kernel(float* __restrict__ out,
                                                 const float* __restrict__ gamma,
                                                 const float* __restrict__ beta) {
    int row = blockIdx.x * 4 + (threadIdx.x >> 6);
    int lane = threadIdx.x & 63;
    float* p = out + (size_t)row * 256;
    float4 v = ((const float4*)p)[lane];
    float s = (v.x + v.y) + (v.z + v.w);
    float s2 = (v.x * v.x + v.y * v.y) + (v.z * v.z + v.w * v.w);
    #pragma unroll
    for (int o = 32; o > 0; o >>= 1) {
        s += __shfl_xor(s, o);
        s2 += __shfl_xor(s2, o);
    }
    float mu = s * (1.f / 256.f);
    float var = s2 * (1.f / 256.f) - mu * mu;
    float rs = rsqrtf(var + 1e-5f);
    float4 gv = ((const float4*)gamma)[lane];
    float4 bv = ((const float4*)beta)[lane];
    float4 r;
    r.x = (v.x - mu) * rs * gv.x + bv.x;
    r.y = (v.y - mu) * rs * gv.y + bv.y;
    r.z = (v.z - mu) * rs * gv.z + bv.z;
    r.w = (v.w - mu) * rs * gv.w + bv.w;
    ((float4*)p)[lane] = r;
}

// ---------------------------------------------------------------------------
extern "C" void kernel_launch(void* const* d_in, const int* in_sizes, int n_in,
                              void* d_out, int out_size, void* d_ws, size_t ws_size,
                              hipStream_t stream) {
    (void)in_sizes; (void)n_in; (void)out_size; (void)ws_size;
    const float* x     = (const float*)d_in[0];
    const float* Wproj = (const float*)d_in[1];
    const float* bproj = (const float*)d_in[2];
    const float* Wih_f = (const float*)d_in[3];
    const float* Whh_f = (const float*)d_in[4];
    const float* b_f   = (const float*)d_in[5];
    const float* Wih_b = (const float*)d_in[6];
    const float* Whh_b = (const float*)d_in[7];
    const float* b_b   = (const float*)d_in[8];
    const float* gamma = (const float*)d_in[9];
    const float* beta  = (const float*)d_in[10];
    float* out = (float*)d_out;

    // workspace layout
    char* ws = (char*)d_ws;
    unsigned short* pre  = (unsigned short*)ws;                   // 65536*1024*2 = 134217728
    unsigned short* xbt  = (unsigned short*)(ws + 134217728);     // 65536*256*2  =  33554432
    unsigned short* weff = (unsigned short*)(ws + 167772160);     // 1024*256*2   =    524288
    float*          beff = (float*)(ws + 168296448);              // 1024*4

    convert_kernel<<<16384, 256, 0, stream>>>(x, xbt);
    fold_kernel<<<1024, 256, 0, stream>>>(Wproj, bproj, Wih_f, b_f, Wih_b, b_b, weff, beff);
    gemm_pre<<<dim3(8, 512), 256, 0, stream>>>(xbt, weff, beff, pre);
    scan_kernel<<<dim3(128, 2), 512, 0, stream>>>(pre, Whh_f, Whh_b, out);
    ln_kernel<<<16384, 256, 0, stream>>>(out, gamma, beta);
}